// Round 8
// baseline (764.263 us; speedup 1.0000x reference)
//
#include <hip/hip_runtime.h>
#include <cstdint>
#include <cstddef>
#include <math.h>

typedef __attribute__((ext_vector_type(8))) short short8;
typedef __attribute__((ext_vector_type(4))) float floatx4;
typedef unsigned short ushort_t;

__device__ __forceinline__ ushort_t f2bf(float x) {
    union { float f; unsigned u; } v; v.f = x;
    unsigned r = v.u + 0x7FFF + ((v.u >> 16) & 1);
    return (ushort_t)(r >> 16);
}
__device__ __forceinline__ float bf2f(ushort_t h) {
    union { unsigned u; float f; } v; v.u = ((unsigned)h) << 16; return v.f;
}
__device__ __forceinline__ void split2(float v, ushort_t& h, ushort_t& l) {
    h = f2bf(v);
    l = f2bf(v - bf2f(h));
}

#define MFMA(a, b, c) __builtin_amdgcn_mfma_f32_16x16x32_bf16((a), (b), (c), 0, 0, 0)

// ---------------------------------------------------------------------
// prep_all: all weight hi/lo splits + Wm transpose + BN fold, one launch.
// ---------------------------------------------------------------------
__global__ void prep_all_kernel(
    const float* __restrict__ Wq, const float* __restrict__ Ws,
    const float* __restrict__ Wg, const float* __restrict__ Wfi,
    const float* __restrict__ Wm,
    const float* bq, const float* bs,
    const float* bg, const float* gg, const float* gb, const float* gm, const float* gv,
    const float* bfi, const float* fg, const float* fb, const float* fm, const float* fv,
    const float* bm, const float* mg, const float* mb, const float* mm, const float* mv,
    ushort_t* Wq_h, ushort_t* Wq_l, ushort_t* Ws_h, ushort_t* Ws_l,
    ushort_t* Wg_h, ushort_t* Wg_l, ushort_t* Wfi_h, ushort_t* Wfi_l,
    ushort_t* wm_h, ushort_t* wm_l, float* scsh)
{
    int bid = blockIdx.x, t = threadIdx.x;
    if (bid < 256) {
        int i = bid * 256 + t; ushort_t h, l; split2(Wq[i], h, l); Wq_h[i] = h; Wq_l[i] = l;
    } else if (bid < 512) {
        int i = (bid - 256) * 256 + t; ushort_t h, l; split2(Ws[i], h, l); Ws_h[i] = h; Ws_l[i] = l;
    } else if (bid < 768) {
        int i = (bid - 512) * 256 + t; ushort_t h, l; split2(Wg[i], h, l); Wg_h[i] = h; Wg_l[i] = l;
    } else if (bid < 1280) {
        int i = (bid - 768) * 256 + t; ushort_t h, l; split2(Wfi[i], h, l); Wfi_h[i] = h; Wfi_l[i] = l;
    } else if (bid < 1856) {
        int i = (bid - 1280) * 256 + t;  // [tap][m][c] flattened
        int c = i & 255, m = (i >> 8) & 63, tap = i >> 14;
        ushort_t h, l; split2(Wm[((size_t)m * 256 + c) * 9 + tap], h, l);
        wm_h[i] = h; wm_l[i] = l;
    } else {
        if (t < 256) {
            scsh[t] = 1.f;        scsh[256 + t] = bq[t];
            scsh[512 + t] = 1.f;  scsh[768 + t] = bs[t];
            float s = gg[t] * rsqrtf(gv[t] + 1e-5f);
            scsh[1024 + t] = s;   scsh[1280 + t] = gb[t] + s * (bg[t] - gm[t]);
            float s2 = fg[t] * rsqrtf(fv[t] + 1e-5f);
            scsh[1536 + t] = s2;  scsh[1792 + t] = fb[t] + s2 * (bfi[t] - fm[t]);
            if (t < 64) {
                float s3 = mg[t] * rsqrtf(mv[t] + 1e-5f);
                scsh[2048 + t] = s3; scsh[2112 + t] = mb[t] + s3 * (bm[t] - mm[t]);
            }
        }
    }
}

// halo-only zero of gxT (128 halo rows per batch, hi+lo)
__global__ void halo_zero_kernel(ushort_t* __restrict__ gxh, ushort_t* __restrict__ gxl) {
    int i = blockIdx.x * 256 + threadIdx.x;   // 0..4095
    int b = i >> 7, k = i & 127;
    int r;
    if (k < 33) r = k;
    else if (k < 66) r = 32 * 33 + (k - 33);
    else { int k2 = k - 66; r = ((k2 >> 1) + 1) * 33 + ((k2 & 1) ? 32 : 0); }
    uint4* ph = (uint4*)(gxh + ((size_t)b * 1089 + r) * 256);
    uint4* pl = (uint4*)(gxl + ((size_t)b * 1089 + r) * 256);
    uint4 z = make_uint4(0, 0, 0, 0);
#pragma unroll
    for (int s = 0; s < 32; s++) { ph[s] = z; pl[s] = z; }
}

// fp32 [B][256][Nsrc] -> bf16 hi/lo [B][Npad][256]
__global__ __launch_bounds__(256) void transpose_in_kernel(
    const float* __restrict__ in, ushort_t* __restrict__ oh, ushort_t* __restrict__ ol,
    int Nsrc, int Npad)
{
    int b = blockIdx.z;
    const float* ib = in + (size_t)b * 256 * Nsrc;
    ushort_t* obh = oh + (size_t)b * Npad * 256;
    ushort_t* obl = ol + (size_t)b * Npad * 256;
    __shared__ float tile[32][33];
    int n0 = blockIdx.x * 32, c0 = blockIdx.y * 32;
    int tx = threadIdx.x & 31, ty = threadIdx.x >> 5;
#pragma unroll
    for (int r = 0; r < 4; r++) {
        int c = c0 + ty + r * 8, n = n0 + tx;
        tile[ty + r * 8][tx] = (n < Nsrc) ? ib[(size_t)c * Nsrc + n] : 0.f;
    }
    __syncthreads();
#pragma unroll
    for (int r = 0; r < 4; r++) {
        int n = n0 + ty + r * 8, c = c0 + tx;
        if (n < Nsrc) {
            ushort_t h, l; split2(tile[tx][ty + r * 8], h, l);
            obh[(size_t)n * 256 + c] = h;
            obl[(size_t)n * 256 + c] = l;
        }
    }
}

// ---------------------------------------------------------------------
// dual conv1x1: O1 = act1(W1@X), O2 = act2(W2@X) sharing X B-tiles.
// ---------------------------------------------------------------------
__global__ __launch_bounds__(512) void dualconv_mfma_kernel(
    const ushort_t* __restrict__ Xh, const ushort_t* __restrict__ Xl,
    const ushort_t* __restrict__ W1h, const ushort_t* __restrict__ W1l,
    const ushort_t* __restrict__ W2h, const ushort_t* __restrict__ W2l,
    const float* __restrict__ sc1, const float* __restrict__ sh1,
    const float* __restrict__ sc2, const float* __restrict__ sh2,
    int relu1, int relu2,
    ushort_t* __restrict__ O1h, ushort_t* __restrict__ O1l,
    ushort_t* __restrict__ O2h, ushort_t* __restrict__ O2l,
    ushort_t* __restrict__ O2ch, ushort_t* __restrict__ O2cl, int cpitch,
    int K, int Nvalid, int NpadIn, int NpadOut)
{
    int b = blockIdx.z;
    const ushort_t* Xbh = Xh + (size_t)b * NpadIn * K;
    const ushort_t* Xbl = Xl + (size_t)b * NpadIn * K;
    int tid = threadIdx.x, w = tid >> 6, l = tid & 63, lc = l & 15, q = l >> 4;
    int half = w >> 2;
    int m0 = (w & 3) * 64, nb0 = blockIdx.x * 32;

    const ushort_t* Wh = half ? W2h : W1h;
    const ushort_t* Wl = half ? W2l : W1l;
    const float* sc = half ? sc2 : sc1;
    const float* sh = half ? sh2 : sh1;
    int relu = half ? relu2 : relu1;
    ushort_t* Obh = (half ? O2h : O1h) + (size_t)b * NpadOut * 256;
    ushort_t* Obl = (half ? O2l : O1l) + (size_t)b * NpadOut * 256;

    floatx4 acc[4][2];
#pragma unroll
    for (int i = 0; i < 4; i++)
#pragma unroll
        for (int j = 0; j < 2; j++) acc[i][j] = (floatx4){0.f, 0.f, 0.f, 0.f};

    for (int k0 = 0; k0 < K; k0 += 32) {
        short8 ah[4], al[4], bh[2], bl[2];
#pragma unroll
        for (int mt = 0; mt < 4; mt++) {
            size_t off = (size_t)(m0 + mt * 16 + lc) * K + k0 + q * 8;
            ah[mt] = *(const short8*)(Wh + off);
            al[mt] = *(const short8*)(Wl + off);
        }
#pragma unroll
        for (int jt = 0; jt < 2; jt++) {
            size_t off = (size_t)(nb0 + jt * 16 + lc) * K + k0 + q * 8;
            bh[jt] = *(const short8*)(Xbh + off);
            bl[jt] = *(const short8*)(Xbl + off);
        }
#pragma unroll
        for (int mt = 0; mt < 4; mt++)
#pragma unroll
            for (int jt = 0; jt < 2; jt++) {
                acc[mt][jt] = MFMA(ah[mt], bh[jt], acc[mt][jt]);
                acc[mt][jt] = MFMA(ah[mt], bl[jt], acc[mt][jt]);
                acc[mt][jt] = MFMA(al[mt], bh[jt], acc[mt][jt]);
            }
    }
#pragma unroll
    for (int mt = 0; mt < 4; mt++) {
        int mb = m0 + mt * 16 + q * 4;
        float s0 = sc[mb], s1 = sc[mb + 1], s2 = sc[mb + 2], s3 = sc[mb + 3];
        float h0 = sh[mb], h1 = sh[mb + 1], h2 = sh[mb + 2], h3 = sh[mb + 3];
#pragma unroll
        for (int jt = 0; jt < 2; jt++) {
            int n = nb0 + jt * 16 + lc;
            if (n >= Nvalid) continue;
            float v0 = acc[mt][jt][0] * s0 + h0;
            float v1 = acc[mt][jt][1] * s1 + h1;
            float v2 = acc[mt][jt][2] * s2 + h2;
            float v3 = acc[mt][jt][3] * s3 + h3;
            if (relu) { v0 = fmaxf(v0, 0.f); v1 = fmaxf(v1, 0.f); v2 = fmaxf(v2, 0.f); v3 = fmaxf(v3, 0.f); }
            ushort_t e0, f0, e1, f1, e2, f2, e3, f3;
            split2(v0, e0, f0); split2(v1, e1, f1); split2(v2, e2, f2); split2(v3, e3, f3);
            *(ushort4*)(Obh + (size_t)n * 256 + mb) = make_ushort4(e0, e1, e2, e3);
            *(ushort4*)(Obl + (size_t)n * 256 + mb) = make_ushort4(f0, f1, f2, f3);
            if (half && O2ch) {
                O2ch[((size_t)b * 256 + mb + 0) * cpitch + n] = e0;
                O2ch[((size_t)b * 256 + mb + 1) * cpitch + n] = e1;
                O2ch[((size_t)b * 256 + mb + 2) * cpitch + n] = e2;
                O2ch[((size_t)b * 256 + mb + 3) * cpitch + n] = e3;
                O2cl[((size_t)b * 256 + mb + 0) * cpitch + n] = f0;
                O2cl[((size_t)b * 256 + mb + 1) * cpitch + n] = f1;
                O2cl[((size_t)b * 256 + mb + 2) * cpitch + n] = f2;
                O2cl[((size_t)b * 256 + mb + 3) * cpitch + n] = f3;
            }
        }
    }
}

// ---------------------------------------------------------------------
// attention via MFMA: sim GEMM (K=256, hi/lo) -> fp32 softmax -> emb GEMM
// ---------------------------------------------------------------------
__global__ __launch_bounds__(256) void attn_mfma_kernel(
    const ushort_t* __restrict__ xth, const ushort_t* __restrict__ xtl,
    const ushort_t* __restrict__ zth, const ushort_t* __restrict__ ztl,
    const ushort_t* __restrict__ zgh, const ushort_t* __restrict__ zgl,
    ushort_t* __restrict__ eh, ushort_t* __restrict__ el)
{
    __shared__ float S[64][68];
    __shared__ ushort_t awh[64][72], awl[64][72];
    __shared__ float T[4][16][20];
    int b = blockIdx.y, n0 = blockIdx.x * 64;
    int tid = threadIdx.x, w = tid >> 6, l = tid & 63, lc = l & 15, q = l >> 4;
    const ushort_t* xhb = xth + (size_t)b * 992 * 256;
    const ushort_t* xlb = xtl + (size_t)b * 992 * 256;
    const ushort_t* zhb = zth + (size_t)b * 64 * 256;
    const ushort_t* zlb = ztl + (size_t)b * 64 * 256;
    const ushort_t* ghb = zgh + (size_t)b * 256 * 64;
    const ushort_t* glb = zgl + (size_t)b * 256 * 64;

    int rowg = n0 + w * 16 + lc;
#pragma unroll
    for (int ct = 0; ct < 4; ct++) {
        floatx4 acc = (floatx4){0.f, 0.f, 0.f, 0.f};
        for (int k0 = 0; k0 < 256; k0 += 32) {
            short8 ah = *(const short8*)(xhb + (size_t)rowg * 256 + k0 + q * 8);
            short8 al = *(const short8*)(xlb + (size_t)rowg * 256 + k0 + q * 8);
            short8 bh = *(const short8*)(zhb + (size_t)(ct * 16 + lc) * 256 + k0 + q * 8);
            short8 bl = *(const short8*)(zlb + (size_t)(ct * 16 + lc) * 256 + k0 + q * 8);
            acc = MFMA(ah, bh, acc);
            acc = MFMA(ah, bl, acc);
            acc = MFMA(al, bh, acc);
        }
#pragma unroll
        for (int r = 0; r < 4; r++) S[w * 16 + q * 4 + r][ct * 16 + lc] = acc[r];
    }
    __syncthreads();
    if (tid < 64) {
        float mx = -INFINITY;
        for (int m = 0; m < 49; m++) mx = fmaxf(mx, S[tid][m]);
        float sum = 0.f;
        for (int m = 0; m < 49; m++) { float e = __expf(S[tid][m] - mx); S[tid][m] = e; sum += e; }
        float inv = 1.f / sum;
        for (int m = 0; m < 64; m++) {
            float vv = (m < 49) ? S[tid][m] * inv : 0.f;
            ushort_t hh, ll; split2(vv, hh, ll);
            awh[tid][m] = hh; awl[tid][m] = ll;
        }
    }
    __syncthreads();
    int nw = l >> 2, cg = l & 3;
#pragma unroll
    for (int ct = 0; ct < 16; ct++) {
        floatx4 acc = (floatx4){0.f, 0.f, 0.f, 0.f};
#pragma unroll
        for (int k0 = 0; k0 < 64; k0 += 32) {
            short8 ah = *(const short8*)(&awh[w * 16 + lc][k0 + q * 8]);
            short8 al = *(const short8*)(&awl[w * 16 + lc][k0 + q * 8]);
            short8 bh = *(const short8*)(ghb + (size_t)(ct * 16 + lc) * 64 + k0 + q * 8);
            short8 bl = *(const short8*)(glb + (size_t)(ct * 16 + lc) * 64 + k0 + q * 8);
            acc = MFMA(ah, bh, acc);
            acc = MFMA(ah, bl, acc);
            acc = MFMA(al, bh, acc);
        }
#pragma unroll
        for (int r = 0; r < 4; r++) T[w][q * 4 + r][lc] = acc[r];
        float4 vv = *(const float4*)&T[w][nw][cg * 4];
        int n = n0 + w * 16 + nw;
        if (n < 961) {
            ushort_t h0, l0, h1, l1, h2, l2_, h3, l3;
            split2(vv.x, h0, l0); split2(vv.y, h1, l1);
            split2(vv.z, h2, l2_); split2(vv.w, h3, l3);
            size_t off = ((size_t)b * 992 + n) * 256 + ct * 16 + cg * 4;
            *(ushort4*)(eh + off) = make_ushort4(h0, h1, h2, h3);
            *(ushort4*)(el + off) = make_ushort4(l0, l1, l2_, l3);
        }
    }
}

// ---------------------------------------------------------------------
// fi conv (K=512 concat(emb, xf_g), hi/lo) -> gxT halo hi/lo + gat_nf bf16
// ---------------------------------------------------------------------
__global__ __launch_bounds__(256) void fi_mfma_kernel(
    const ushort_t* __restrict__ Eh, const ushort_t* __restrict__ El,
    const ushort_t* __restrict__ Gh, const ushort_t* __restrict__ Gl,
    const ushort_t* __restrict__ Wh, const ushort_t* __restrict__ Wl,
    const float* __restrict__ sc, const float* __restrict__ sh,
    ushort_t* __restrict__ gxh, ushort_t* __restrict__ gxl,
    ushort_t* __restrict__ gat_nf)
{
    int b = blockIdx.z;
    const ushort_t* Ebh = Eh + (size_t)b * 992 * 256;
    const ushort_t* Ebl = El + (size_t)b * 992 * 256;
    const ushort_t* Gbh = Gh + (size_t)b * 992 * 256;
    const ushort_t* Gbl = Gl + (size_t)b * 992 * 256;
    ushort_t* gxhb = gxh + (size_t)b * 1089 * 256;
    ushort_t* gxlb = gxl + (size_t)b * 1089 * 256;
    ushort_t* gn = gat_nf + (size_t)b * 256 * 992;
    int tid = threadIdx.x, w = tid >> 6, l = tid & 63, lc = l & 15, q = l >> 4;
    int m0 = w * 64, nb0 = blockIdx.x * 32;

    floatx4 acc[4][2];
#pragma unroll
    for (int i = 0; i < 4; i++)
#pragma unroll
        for (int j = 0; j < 2; j++) acc[i][j] = (floatx4){0.f, 0.f, 0.f, 0.f};

    for (int k0 = 0; k0 < 512; k0 += 32) {
        const ushort_t* sh_ = (k0 < 256) ? Ebh : Gbh;
        const ushort_t* sl_ = (k0 < 256) ? Ebl : Gbl;
        int kk = (k0 < 256) ? k0 : k0 - 256;
        short8 ah[4], al[4], bh[2], bl[2];
#pragma unroll
        for (int mt = 0; mt < 4; mt++) {
            size_t off = (size_t)(m0 + mt * 16 + lc) * 512 + k0 + q * 8;
            ah[mt] = *(const short8*)(Wh + off);
            al[mt] = *(const short8*)(Wl + off);
        }
#pragma unroll
        for (int jt = 0; jt < 2; jt++) {
            size_t off = (size_t)(nb0 + jt * 16 + lc) * 256 + kk + q * 8;
            bh[jt] = *(const short8*)(sh_ + off);
            bl[jt] = *(const short8*)(sl_ + off);
        }
#pragma unroll
        for (int mt = 0; mt < 4; mt++)
#pragma unroll
            for (int jt = 0; jt < 2; jt++) {
                acc[mt][jt] = MFMA(ah[mt], bh[jt], acc[mt][jt]);
                acc[mt][jt] = MFMA(ah[mt], bl[jt], acc[mt][jt]);
                acc[mt][jt] = MFMA(al[mt], bh[jt], acc[mt][jt]);
            }
    }
#pragma unroll
    for (int mt = 0; mt < 4; mt++) {
        int mb = m0 + mt * 16 + q * 4;
        float s0 = sc[mb], s1 = sc[mb + 1], s2 = sc[mb + 2], s3 = sc[mb + 3];
        float h0 = sh[mb], h1 = sh[mb + 1], h2 = sh[mb + 2], h3 = sh[mb + 3];
#pragma unroll
        for (int jt = 0; jt < 2; jt++) {
            int n = nb0 + jt * 16 + lc;
            if (n >= 961) continue;
            float v0 = fmaxf(acc[mt][jt][0] * s0 + h0, 0.f);
            float v1 = fmaxf(acc[mt][jt][1] * s1 + h1, 0.f);
            float v2 = fmaxf(acc[mt][jt][2] * s2 + h2, 0.f);
            float v3 = fmaxf(acc[mt][jt][3] * s3 + h3, 0.f);
            ushort_t a0, b0, a1, b1, a2, b2, a3, b3;
            split2(v0, a0, b0); split2(v1, a1, b1); split2(v2, a2, b2); split2(v3, a3, b3);
            int hh = n / 31, ww2 = n - hh * 31;
            int row = (hh + 1) * 33 + (ww2 + 1);
            *(ushort4*)(gxhb + (size_t)row * 256 + mb) = make_ushort4(a0, a1, a2, a3);
            *(ushort4*)(gxlb + (size_t)row * 256 + mb) = make_ushort4(b0, b1, b2, b3);
            gn[(size_t)(mb + 0) * 992 + n] = a0;
            gn[(size_t)(mb + 1) * 992 + n] = a1;
            gn[(size_t)(mb + 2) * 992 + n] = a2;
            gn[(size_t)(mb + 3) * 992 + n] = a3;
        }
    }
}

// ---------------------------------------------------------------------
// conv3x3 via 9-tap 3-term MFMA over halo gxT hi/lo -> eT hi/lo [j][64]
// RE-TILED for occupancy: wave = 32m x 16j, block = 4 waves = 64m x 32j,
// grid (31,1,32) = 992 blocks (~15.5 waves/CU vs 4 before).
// ---------------------------------------------------------------------
__global__ __launch_bounds__(256) void conv3x3_mfma_kernel(
    const ushort_t* __restrict__ gxh, const ushort_t* __restrict__ gxl,
    const ushort_t* __restrict__ wmh, const ushort_t* __restrict__ wml,
    const float* __restrict__ sc, const float* __restrict__ sh,
    const float* __restrict__ prelu_a,
    ushort_t* __restrict__ eh, ushort_t* __restrict__ el)
{
    int b = blockIdx.z;
    const ushort_t* gxhb = gxh + (size_t)b * 1089 * 256;
    const ushort_t* gxlb = gxl + (size_t)b * 1089 * 256;
    ushort_t* ebh = eh + (size_t)b * 1024 * 64;
    ushort_t* ebl = el + (size_t)b * 1024 * 64;
    int tid = threadIdx.x, w = tid >> 6, l = tid & 63, lc = l & 15, q = l >> 4;
    int mh = w >> 1;               // m half: 0 -> rows 0-31, 1 -> rows 32-63
    int jq = w & 1;                // j quarter within block's 32-j span
    int j0 = blockIdx.x * 32 + jq * 16;

    int jj = j0 + lc; if (jj > 960) jj = 960;
    int hh0 = jj / 31, ww0 = jj - hh0 * 31;

    floatx4 acc[2];
    acc[0] = (floatx4){0.f, 0.f, 0.f, 0.f};
    acc[1] = (floatx4){0.f, 0.f, 0.f, 0.f};

    for (int tap = 0; tap < 9; tap++) {
        int dh = tap / 3 - 1, dw = tap % 3 - 1;
        int srow = (hh0 + 1 + dh) * 33 + (ww0 + 1 + dw);
        const ushort_t* wth = wmh + tap * 16384;
        const ushort_t* wtl = wml + tap * 16384;
        for (int k0 = 0; k0 < 256; k0 += 32) {
            short8 ah[2], al_[2], bh, bl;
#pragma unroll
            for (int mt = 0; mt < 2; mt++) {
                size_t off = (size_t)(mh * 32 + mt * 16 + lc) * 256 + k0 + q * 8;
                ah[mt]  = *(const short8*)(wth + off);
                al_[mt] = *(const short8*)(wtl + off);
            }
            {
                size_t off = (size_t)srow * 256 + k0 + q * 8;
                bh = *(const short8*)(gxhb + off);
                bl = *(const short8*)(gxlb + off);
            }
#pragma unroll
            for (int mt = 0; mt < 2; mt++) {
                acc[mt] = MFMA(ah[mt], bh, acc[mt]);
                acc[mt] = MFMA(ah[mt], bl, acc[mt]);
                acc[mt] = MFMA(al_[mt], bh, acc[mt]);
            }
        }
    }
    float pa = prelu_a[0];
    int j = j0 + lc;
#pragma unroll
    for (int mt = 0; mt < 2; mt++) {
        int mb = mh * 32 + mt * 16 + q * 4;
        float s0 = sc[mb], s1 = sc[mb + 1], s2 = sc[mb + 2], s3 = sc[mb + 3];
        float h0 = sh[mb], h1 = sh[mb + 1], h2 = sh[mb + 2], h3 = sh[mb + 3];
        if (j >= 961) continue;
        float v0 = acc[mt][0] * s0 + h0; v0 = v0 >= 0.f ? v0 : pa * v0;
        float v1 = acc[mt][1] * s1 + h1; v1 = v1 >= 0.f ? v1 : pa * v1;
        float v2 = acc[mt][2] * s2 + h2; v2 = v2 >= 0.f ? v2 : pa * v2;
        float v3 = acc[mt][3] * s3 + h3; v3 = v3 >= 0.f ? v3 : pa * v3;
        ushort_t a0, b0, a1, b1, a2, b2, a3, b3;
        split2(v0, a0, b0); split2(v1, a1, b1); split2(v2, a2, b2); split2(v3, a3, b3);
        *(ushort4*)(ebh + (size_t)j * 64 + mb) = make_ushort4(a0, a1, a2, a3);
        *(ushort4*)(ebl + (size_t)j * 64 + mb) = make_ushort4(b0, b1, b2, b3);
    }
}

// ---------------------------------------------------------------------
// HSPA: S = e^T e (3-term hi/lo MFMA) -> sparsemax via Michelot/Newton
// ---------------------------------------------------------------------
__global__ __launch_bounds__(512) void hspa_mfma_kernel(
    const ushort_t* __restrict__ eh, const ushort_t* __restrict__ el,
    ushort_t* __restrict__ PT)
{
    const int PITCH = 978;
    __shared__ float S[16 * 978];
    int b = blockIdx.y, nb = blockIdx.x;
    const ushort_t* ebh = eh + (size_t)b * 1024 * 64;
    const ushort_t* ebl = el + (size_t)b * 1024 * 64;
    ushort_t* Pb = PT + (size_t)b * 1024 * 992;
    int tid = threadIdx.x, w = tid >> 6, l = tid & 63, lc = l & 15, q = l >> 4;
    int n0 = nb * 16;

    short8 a0h = *(const short8*)(ebh + (size_t)(n0 + lc) * 64 + q * 8);
    short8 a0l = *(const short8*)(ebl + (size_t)(n0 + lc) * 64 + q * 8);
    short8 a1h = *(const short8*)(ebh + (size_t)(n0 + lc) * 64 + 32 + q * 8);
    short8 a1l = *(const short8*)(ebl + (size_t)(n0 + lc) * 64 + 32 + q * 8);

    for (int jt = w; jt < 61; jt += 8) {
        int j = jt * 16 + lc;
        short8 b0h = *(const short8*)(ebh + (size_t)j * 64 + q * 8);
        short8 b0l = *(const short8*)(ebl + (size_t)j * 64 + q * 8);
        short8 b1h = *(const short8*)(ebh + (size_t)j * 64 + 32 + q * 8);
        short8 b1l = *(const short8*)(ebl + (size_t)j * 64 + 32 + q * 8);
        floatx4 acc = (floatx4){0.f, 0.f, 0.f, 0.f};
        acc = MFMA(a0h, b0h, acc);
        acc = MFMA(a0h, b0l, acc);
        acc = MFMA(a0l, b0h, acc);
        acc = MFMA(a1h, b1h, acc);
        acc = MFMA(a1h, b1l, acc);
        acc = MFMA(a1l, b1h, acc);
#pragma unroll
        for (int r = 0; r < 4; r++) S[(q * 4 + r) * PITCH + j] = acc[r];
    }
    __syncthreads();

    int r0 = w * 2, r1 = w * 2 + 1;
    float sv0[16], sv1[16];
    float mx0 = -INFINITY, mx1 = -INFINITY;
#pragma unroll
    for (int t = 0; t < 16; t++) {
        int j = l + t * 64;
        float s0 = (j < 961) ? S[r0 * PITCH + j] : -INFINITY;
        float s1 = (j < 961) ? S[r1 * PITCH + j] : -INFINITY;
        sv0[t] = s0; sv1[t] = s1;
        mx0 = fmaxf(mx0, s0); mx1 = fmaxf(mx1, s1);
    }
    for (int off = 32; off; off >>= 1) {
        mx0 = fmaxf(mx0, __shfl_xor(mx0, off));
        mx1 = fmaxf(mx1, __shfl_xor(mx1, off));
    }
#pragma unroll
    for (int t = 0; t < 16; t++) { sv0[t] -= mx0; sv1[t] -= mx1; }

    float tau0 = -1.f, tau1 = -1.f;
    for (int it = 0; it < 16; it++) {
        float s0 = 0.f, c0 = 0.f, s1 = 0.f, c1 = 0.f;
#pragma unroll
        for (int t = 0; t < 16; t++) {
            if (sv0[t] > tau0) { s0 += sv0[t]; c0 += 1.f; }
            if (sv1[t] > tau1) { s1 += sv1[t]; c1 += 1.f; }
        }
        for (int off = 32; off; off >>= 1) {
            s0 += __shfl_xor(s0, off); c0 += __shfl_xor(c0, off);
            s1 += __shfl_xor(s1, off); c1 += __shfl_xor(c1, off);
        }
        float nt0 = (s0 - 1.f) / c0;
        float nt1 = (s1 - 1.f) / c1;
        bool conv = (nt0 == tau0) && (nt1 == tau1);
        tau0 = nt0; tau1 = nt1;
        if (conv) break;
    }
#pragma unroll
    for (int t = 0; t < 16; t++) {
        int j = l + t * 64;
        if (j < 976) {
            S[r0 * PITCH + j] = (j < 961) ? fmaxf(sv0[t] - tau0, 0.f) : 0.f;
            S[r1 * PITCH + j] = (j < 961) ? fmaxf(sv1[t] - tau1, 0.f) : 0.f;
        }
    }
    __syncthreads();

    for (int j = tid; j < 976; j += 512) {
        union { ushort_t u[8]; uint4 v; } p0, p1;
#pragma unroll
        for (int r = 0; r < 8; r++)  p0.u[r] = f2bf(S[r * PITCH + j]);
#pragma unroll
        for (int r = 0; r < 8; r++)  p1.u[r] = f2bf(S[(8 + r) * PITCH + j]);
        ushort_t* dst = Pb + (size_t)j * 992 + n0;
        *(uint4*)(dst) = p0.v;
        *(uint4*)(dst + 8) = p1.v;
    }
}

// ---------------------------------------------------------------------
// out = gat @ P + gat. Single bf16 MFMA (incoherent noise OK).
// ---------------------------------------------------------------------
__global__ __launch_bounds__(256) void out_mfma_kernel(
    const ushort_t* __restrict__ gat_nf, const ushort_t* __restrict__ PT,
    float* __restrict__ out)
{
    int b = blockIdx.z, jb = blockIdx.x;
    const ushort_t* gb = gat_nf + (size_t)b * 256 * 992;
    const ushort_t* Pb = PT + (size_t)b * 1024 * 992;
    float* ob = out + (size_t)b * 256 * 961;
    int tid = threadIdx.x, w = tid >> 6, l = tid & 63, lc = l & 15, q = l >> 4;
    int m0 = w * 64, j0 = jb * 64;

    floatx4 acc[4][4];
#pragma unroll
    for (int i = 0; i < 4; i++)
#pragma unroll
        for (int j = 0; j < 4; j++) acc[i][j] = (floatx4){0.f, 0.f, 0.f, 0.f};

    for (int k0 = 0; k0 < 992; k0 += 32) {
        short8 a[4], bb[4];
#pragma unroll
        for (int mt = 0; mt < 4; mt++)
            a[mt] = *(const short8*)(gb + (size_t)(m0 + mt * 16 + lc) * 992 + k0 + q * 8);
#pragma unroll
        for (int jt = 0; jt < 4; jt++)
            bb[jt] = *(const short8*)(Pb + (size_t)(j0 + jt * 16 + lc) * 992 + k0 + q * 8);
#pragma unroll
        for (int mt = 0; mt < 4; mt++)
#pragma unroll
            for (int jt = 0; jt < 4; jt++)
                acc[mt][jt] = MFMA(a[mt], bb[jt], acc[mt][jt]);
    }
#pragma unroll
    for (int mt = 0; mt < 4; mt++) {
        int mb = m0 + mt * 16 + q * 4;
#pragma unroll
        for (int jt = 0; jt < 4; jt++) {
            int j = j0 + jt * 16 + lc;
            if (j >= 961) continue;
#pragma unroll
            for (int r = 0; r < 4; r++) {
                float g = bf2f(gb[(size_t)(mb + r) * 992 + j]);
                ob[(size_t)(mb + r) * 961 + j] = acc[mt][jt][r] + g;
            }
        }
    }
}

// =====================================================================
extern "C" void kernel_launch(void* const* d_in, const int* in_sizes, int n_in,
                              void* d_out, int out_size, void* d_ws, size_t ws_size,
                              hipStream_t stream)
{
    const float* zf      = (const float*)d_in[0];
    const float* xf      = (const float*)d_in[1];
    const float* Wq      = (const float*)d_in[2];
    const float* bq      = (const float*)d_in[3];
    const float* Ws      = (const float*)d_in[4];
    const float* bs      = (const float*)d_in[5];
    const float* Wg      = (const float*)d_in[6];
    const float* bg      = (const float*)d_in[7];
    const float* g_gamma = (const float*)d_in[8];
    const float* g_beta  = (const float*)d_in[9];
    const float* g_mean  = (const float*)d_in[10];
    const float* g_var   = (const float*)d_in[11];
    const float* Wfi     = (const float*)d_in[12];
    const float* bfi     = (const float*)d_in[13];
    const float* fi_gamma= (const float*)d_in[14];
    const float* fi_beta = (const float*)d_in[15];
    const float* fi_mean = (const float*)d_in[16];
    const float* fi_var  = (const float*)d_in[17];
    const float* Wm      = (const float*)d_in[18];
    const float* bm      = (const float*)d_in[19];
    const float* m_gamma = (const float*)d_in[20];
    const float* m_beta  = (const float*)d_in[21];
    const float* m_mean  = (const float*)d_in[22];
    const float* m_var   = (const float*)d_in[23];
    const float* prelu_a = (const float*)d_in[24];
    float* out = (float*)d_out;

    ushort_t* ws = (ushort_t*)d_ws;
    ushort_t* Wq_h  = ws + 0;         ushort_t* Wq_l  = ws + 65536;
    ushort_t* Ws_h  = ws + 131072;    ushort_t* Ws_l  = ws + 196608;
    ushort_t* Wg_h  = ws + 262144;    ushort_t* Wg_l  = ws + 327680;
    ushort_t* Wfi_h = ws + 393216;    ushort_t* Wfi_l = ws + 524288;
    ushort_t* wm_h  = ws + 655360;    ushort_t* wm_l  = ws + 802816;
    ushort_t* XT_h    = ws + 950272;      // 8,126,464 each
    ushort_t* XT_l    = ws + 9076736;
    ushort_t* xf_tT_h = ws + 17203200;
    ushort_t* xf_tT_l = ws + 25329664;
    ushort_t* zf_tT_h = ws + 33456128;    // 524,288 each
    ushort_t* zf_tT_l = ws + 33980416;
    ushort_t* zf_gT_h = ws + 34504704;
    ushort_t* zf_gT_l = ws + 35028992;
    ushort_t* gxT_h   = ws + 17203200;    // aliases xf_tT region (dead after attn)
    ushort_t* gxT_l   = ws + 26124288;
    ushort_t* xf_gT_h = ws + 35553280;
    ushort_t* xf_gT_l = ws + 43679744;
    ushort_t* gat_nf  = ws + 51806208;    // 8,126,464
    ushort_t* eT_h    = ws + 59932672;    // 2,097,152 each
    ushort_t* eT_l    = ws + 62029824;
    ushort_t* PT      = ws + 64126976;    // 32,505,856
    ushort_t* zfT_h   = ws + 96632832;    // 524,288 each
    ushort_t* zfT_l   = ws + 97157120;
    float* scsh       = (float*)(ws + 97681408);   // 2176 floats
    ushort_t* zgC_h   = ws + 97685760;    // 524,288 each
    ushort_t* zgC_l   = ws + 98210048;
    ushort_t* embT_h = XT_h;
    ushort_t* embT_l = XT_l;

    const float* sc_q  = scsh + 0,    *sh_q  = scsh + 256;
    const float* sc_s  = scsh + 512,  *sh_s  = scsh + 768;
    const float* sc_g  = scsh + 1024, *sh_g  = scsh + 1280;
    const float* sc_fi = scsh + 1536, *sh_fi = scsh + 1792;
    const float* sc_m  = scsh + 2048, *sh_m  = scsh + 2112;

    prep_all_kernel<<<1857, 256, 0, stream>>>(
        Wq, Ws, Wg, Wfi, Wm,
        bq, bs, bg, g_gamma, g_beta, g_mean, g_var,
        bfi, fi_gamma, fi_beta, fi_mean, fi_var,
        bm, m_gamma, m_beta, m_mean, m_var,
        Wq_h, Wq_l, Ws_h, Ws_l, Wg_h, Wg_l, Wfi_h, Wfi_l, wm_h, wm_l, scsh);

    transpose_in_kernel<<<dim3(31, 8, 32), 256, 0, stream>>>(xf, XT_h, XT_l, 961, 992);
    transpose_in_kernel<<<dim3(2, 8, 32), 256, 0, stream>>>(zf, zfT_h, zfT_l, 49, 64);

    dualconv_mfma_kernel<<<dim3(31, 1, 32), 512, 0, stream>>>(
        XT_h, XT_l, Wq_h, Wq_l, Wg_h, Wg_l,
        sc_q, sh_q, sc_g, sh_g, 0, 1,
        xf_tT_h, xf_tT_l, xf_gT_h, xf_gT_l,
        nullptr, nullptr, 0, 256, 961, 992, 992);
    dualconv_mfma_kernel<<<dim3(2, 1, 32), 512, 0, stream>>>(
        zfT_h, zfT_l, Ws_h, Ws_l, Wg_h, Wg_l,
        sc_s, sh_s, sc_g, sh_g, 0, 1,
        zf_tT_h, zf_tT_l, zf_gT_h, zf_gT_l,
        zgC_h, zgC_l, 64, 256, 49, 64, 64);

    attn_mfma_kernel<<<dim3(16, 32), 256, 0, stream>>>(
        xf_tT_h, xf_tT_l, zf_tT_h, zf_tT_l, zgC_h, zgC_l, embT_h, embT_l);

    halo_zero_kernel<<<16, 256, 0, stream>>>(gxT_h, gxT_l);

    fi_mfma_kernel<<<dim3(31, 1, 32), 256, 0, stream>>>(
        embT_h, embT_l, xf_gT_h, xf_gT_l, Wfi_h, Wfi_l, sc_fi, sh_fi,
        gxT_h, gxT_l, gat_nf);

    conv3x3_mfma_kernel<<<dim3(31, 1, 32), 256, 0, stream>>>(
        gxT_h, gxT_l, wm_h, wm_l, sc_m, sh_m, prelu_a, eT_h, eT_l);

    hspa_mfma_kernel<<<dim3(61, 32), 512, 0, stream>>>(eT_h, eT_l, PT);

    out_mfma_kernel<<<dim3(16, 1, 32), 256, 0, stream>>>(gat_nf, PT, out);
}

// Round 9
// 675.202 us; speedup vs baseline: 1.1319x; 1.1319x over previous
//
#include <hip/hip_runtime.h>
#include <cstdint>
#include <cstddef>
#include <math.h>

typedef __attribute__((ext_vector_type(8))) short short8;
typedef __attribute__((ext_vector_type(4))) float floatx4;
typedef unsigned short ushort_t;

__device__ __forceinline__ ushort_t f2bf(float x) {
    union { float f; unsigned u; } v; v.f = x;
    unsigned r = v.u + 0x7FFF + ((v.u >> 16) & 1);
    return (ushort_t)(r >> 16);
}
__device__ __forceinline__ float bf2f(ushort_t h) {
    union { unsigned u; float f; } v; v.u = ((unsigned)h) << 16; return v.f;
}
__device__ __forceinline__ void split2(float v, ushort_t& h, ushort_t& l) {
    h = f2bf(v);
    l = f2bf(v - bf2f(h));
}

#define MFMA(a, b, c) __builtin_amdgcn_mfma_f32_16x16x32_bf16((a), (b), (c), 0, 0, 0)

// ---------------------------------------------------------------------
// prep_all: all weight hi/lo splits + Wm transpose + BN fold, one launch.
// ---------------------------------------------------------------------
__global__ void prep_all_kernel(
    const float* __restrict__ Wq, const float* __restrict__ Ws,
    const float* __restrict__ Wg, const float* __restrict__ Wfi,
    const float* __restrict__ Wm,
    const float* bq, const float* bs,
    const float* bg, const float* gg, const float* gb, const float* gm, const float* gv,
    const float* bfi, const float* fg, const float* fb, const float* fm, const float* fv,
    const float* bm, const float* mg, const float* mb, const float* mm, const float* mv,
    ushort_t* Wq_h, ushort_t* Wq_l, ushort_t* Ws_h, ushort_t* Ws_l,
    ushort_t* Wg_h, ushort_t* Wg_l, ushort_t* Wfi_h, ushort_t* Wfi_l,
    ushort_t* wm_h, ushort_t* wm_l, float* scsh)
{
    int bid = blockIdx.x, t = threadIdx.x;
    if (bid < 256) {
        int i = bid * 256 + t; ushort_t h, l; split2(Wq[i], h, l); Wq_h[i] = h; Wq_l[i] = l;
    } else if (bid < 512) {
        int i = (bid - 256) * 256 + t; ushort_t h, l; split2(Ws[i], h, l); Ws_h[i] = h; Ws_l[i] = l;
    } else if (bid < 768) {
        int i = (bid - 512) * 256 + t; ushort_t h, l; split2(Wg[i], h, l); Wg_h[i] = h; Wg_l[i] = l;
    } else if (bid < 1280) {
        int i = (bid - 768) * 256 + t; ushort_t h, l; split2(Wfi[i], h, l); Wfi_h[i] = h; Wfi_l[i] = l;
    } else if (bid < 1856) {
        int i = (bid - 1280) * 256 + t;  // [tap][m][c] flattened
        int c = i & 255, m = (i >> 8) & 63, tap = i >> 14;
        ushort_t h, l; split2(Wm[((size_t)m * 256 + c) * 9 + tap], h, l);
        wm_h[i] = h; wm_l[i] = l;
    } else {
        if (t < 256) {
            scsh[t] = 1.f;        scsh[256 + t] = bq[t];
            scsh[512 + t] = 1.f;  scsh[768 + t] = bs[t];
            float s = gg[t] * rsqrtf(gv[t] + 1e-5f);
            scsh[1024 + t] = s;   scsh[1280 + t] = gb[t] + s * (bg[t] - gm[t]);
            float s2 = fg[t] * rsqrtf(fv[t] + 1e-5f);
            scsh[1536 + t] = s2;  scsh[1792 + t] = fb[t] + s2 * (bfi[t] - fm[t]);
            if (t < 64) {
                float s3 = mg[t] * rsqrtf(mv[t] + 1e-5f);
                scsh[2048 + t] = s3; scsh[2112 + t] = mb[t] + s3 * (bm[t] - mm[t]);
            }
        }
    }
}

// halo-only zero of gxT (128 halo rows per batch, hi+lo)
__global__ void halo_zero_kernel(ushort_t* __restrict__ gxh, ushort_t* __restrict__ gxl) {
    int i = blockIdx.x * 256 + threadIdx.x;   // 0..4095
    int b = i >> 7, k = i & 127;
    int r;
    if (k < 33) r = k;
    else if (k < 66) r = 32 * 33 + (k - 33);
    else { int k2 = k - 66; r = ((k2 >> 1) + 1) * 33 + ((k2 & 1) ? 32 : 0); }
    uint4* ph = (uint4*)(gxh + ((size_t)b * 1089 + r) * 256);
    uint4* pl = (uint4*)(gxl + ((size_t)b * 1089 + r) * 256);
    uint4 z = make_uint4(0, 0, 0, 0);
#pragma unroll
    for (int s = 0; s < 32; s++) { ph[s] = z; pl[s] = z; }
}

// fp32 [B][256][Nsrc] -> bf16 hi/lo [B][Npad][256]
__global__ __launch_bounds__(256) void transpose_in_kernel(
    const float* __restrict__ in, ushort_t* __restrict__ oh, ushort_t* __restrict__ ol,
    int Nsrc, int Npad)
{
    int b = blockIdx.z;
    const float* ib = in + (size_t)b * 256 * Nsrc;
    ushort_t* obh = oh + (size_t)b * Npad * 256;
    ushort_t* obl = ol + (size_t)b * Npad * 256;
    __shared__ float tile[32][33];
    int n0 = blockIdx.x * 32, c0 = blockIdx.y * 32;
    int tx = threadIdx.x & 31, ty = threadIdx.x >> 5;
#pragma unroll
    for (int r = 0; r < 4; r++) {
        int c = c0 + ty + r * 8, n = n0 + tx;
        tile[ty + r * 8][tx] = (n < Nsrc) ? ib[(size_t)c * Nsrc + n] : 0.f;
    }
    __syncthreads();
#pragma unroll
    for (int r = 0; r < 4; r++) {
        int n = n0 + ty + r * 8, c = c0 + tx;
        if (n < Nsrc) {
            ushort_t h, l; split2(tile[tx][ty + r * 8], h, l);
            obh[(size_t)n * 256 + c] = h;
            obl[(size_t)n * 256 + c] = l;
        }
    }
}

// ---------------------------------------------------------------------
// dual conv1x1: O1 = act1(W1@X), O2 = act2(W2@X) sharing X B-tiles.
// ---------------------------------------------------------------------
__global__ __launch_bounds__(512) void dualconv_mfma_kernel(
    const ushort_t* __restrict__ Xh, const ushort_t* __restrict__ Xl,
    const ushort_t* __restrict__ W1h, const ushort_t* __restrict__ W1l,
    const ushort_t* __restrict__ W2h, const ushort_t* __restrict__ W2l,
    const float* __restrict__ sc1, const float* __restrict__ sh1,
    const float* __restrict__ sc2, const float* __restrict__ sh2,
    int relu1, int relu2,
    ushort_t* __restrict__ O1h, ushort_t* __restrict__ O1l,
    ushort_t* __restrict__ O2h, ushort_t* __restrict__ O2l,
    ushort_t* __restrict__ O2ch, ushort_t* __restrict__ O2cl, int cpitch,
    int K, int Nvalid, int NpadIn, int NpadOut)
{
    int b = blockIdx.z;
    const ushort_t* Xbh = Xh + (size_t)b * NpadIn * K;
    const ushort_t* Xbl = Xl + (size_t)b * NpadIn * K;
    int tid = threadIdx.x, w = tid >> 6, l = tid & 63, lc = l & 15, q = l >> 4;
    int half = w >> 2;
    int m0 = (w & 3) * 64, nb0 = blockIdx.x * 32;

    const ushort_t* Wh = half ? W2h : W1h;
    const ushort_t* Wl = half ? W2l : W1l;
    const float* sc = half ? sc2 : sc1;
    const float* sh = half ? sh2 : sh1;
    int relu = half ? relu2 : relu1;
    ushort_t* Obh = (half ? O2h : O1h) + (size_t)b * NpadOut * 256;
    ushort_t* Obl = (half ? O2l : O1l) + (size_t)b * NpadOut * 256;

    floatx4 acc[4][2];
#pragma unroll
    for (int i = 0; i < 4; i++)
#pragma unroll
        for (int j = 0; j < 2; j++) acc[i][j] = (floatx4){0.f, 0.f, 0.f, 0.f};

    for (int k0 = 0; k0 < K; k0 += 32) {
        short8 ah[4], al[4], bh[2], bl[2];
#pragma unroll
        for (int mt = 0; mt < 4; mt++) {
            size_t off = (size_t)(m0 + mt * 16 + lc) * K + k0 + q * 8;
            ah[mt] = *(const short8*)(Wh + off);
            al[mt] = *(const short8*)(Wl + off);
        }
#pragma unroll
        for (int jt = 0; jt < 2; jt++) {
            size_t off = (size_t)(nb0 + jt * 16 + lc) * K + k0 + q * 8;
            bh[jt] = *(const short8*)(Xbh + off);
            bl[jt] = *(const short8*)(Xbl + off);
        }
#pragma unroll
        for (int mt = 0; mt < 4; mt++)
#pragma unroll
            for (int jt = 0; jt < 2; jt++) {
                acc[mt][jt] = MFMA(ah[mt], bh[jt], acc[mt][jt]);
                acc[mt][jt] = MFMA(ah[mt], bl[jt], acc[mt][jt]);
                acc[mt][jt] = MFMA(al[mt], bh[jt], acc[mt][jt]);
            }
    }
#pragma unroll
    for (int mt = 0; mt < 4; mt++) {
        int mb = m0 + mt * 16 + q * 4;
        float s0 = sc[mb], s1 = sc[mb + 1], s2 = sc[mb + 2], s3 = sc[mb + 3];
        float h0 = sh[mb], h1 = sh[mb + 1], h2 = sh[mb + 2], h3 = sh[mb + 3];
#pragma unroll
        for (int jt = 0; jt < 2; jt++) {
            int n = nb0 + jt * 16 + lc;
            if (n >= Nvalid) continue;
            float v0 = acc[mt][jt][0] * s0 + h0;
            float v1 = acc[mt][jt][1] * s1 + h1;
            float v2 = acc[mt][jt][2] * s2 + h2;
            float v3 = acc[mt][jt][3] * s3 + h3;
            if (relu) { v0 = fmaxf(v0, 0.f); v1 = fmaxf(v1, 0.f); v2 = fmaxf(v2, 0.f); v3 = fmaxf(v3, 0.f); }
            ushort_t e0, f0, e1, f1, e2, f2, e3, f3;
            split2(v0, e0, f0); split2(v1, e1, f1); split2(v2, e2, f2); split2(v3, e3, f3);
            *(ushort4*)(Obh + (size_t)n * 256 + mb) = make_ushort4(e0, e1, e2, e3);
            *(ushort4*)(Obl + (size_t)n * 256 + mb) = make_ushort4(f0, f1, f2, f3);
            if (half && O2ch) {
                O2ch[((size_t)b * 256 + mb + 0) * cpitch + n] = e0;
                O2ch[((size_t)b * 256 + mb + 1) * cpitch + n] = e1;
                O2ch[((size_t)b * 256 + mb + 2) * cpitch + n] = e2;
                O2ch[((size_t)b * 256 + mb + 3) * cpitch + n] = e3;
                O2cl[((size_t)b * 256 + mb + 0) * cpitch + n] = f0;
                O2cl[((size_t)b * 256 + mb + 1) * cpitch + n] = f1;
                O2cl[((size_t)b * 256 + mb + 2) * cpitch + n] = f2;
                O2cl[((size_t)b * 256 + mb + 3) * cpitch + n] = f3;
            }
        }
    }
}

// ---------------------------------------------------------------------
// attention via MFMA: sim GEMM (K=256, hi/lo) -> fp32 softmax -> emb GEMM
// ---------------------------------------------------------------------
__global__ __launch_bounds__(256) void attn_mfma_kernel(
    const ushort_t* __restrict__ xth, const ushort_t* __restrict__ xtl,
    const ushort_t* __restrict__ zth, const ushort_t* __restrict__ ztl,
    const ushort_t* __restrict__ zgh, const ushort_t* __restrict__ zgl,
    ushort_t* __restrict__ eh, ushort_t* __restrict__ el)
{
    __shared__ float S[64][68];
    __shared__ ushort_t awh[64][72], awl[64][72];
    __shared__ float T[4][16][20];
    int b = blockIdx.y, n0 = blockIdx.x * 64;
    int tid = threadIdx.x, w = tid >> 6, l = tid & 63, lc = l & 15, q = l >> 4;
    const ushort_t* xhb = xth + (size_t)b * 992 * 256;
    const ushort_t* xlb = xtl + (size_t)b * 992 * 256;
    const ushort_t* zhb = zth + (size_t)b * 64 * 256;
    const ushort_t* zlb = ztl + (size_t)b * 64 * 256;
    const ushort_t* ghb = zgh + (size_t)b * 256 * 64;
    const ushort_t* glb = zgl + (size_t)b * 256 * 64;

    int rowg = n0 + w * 16 + lc;
#pragma unroll
    for (int ct = 0; ct < 4; ct++) {
        floatx4 acc = (floatx4){0.f, 0.f, 0.f, 0.f};
        for (int k0 = 0; k0 < 256; k0 += 32) {
            short8 ah = *(const short8*)(xhb + (size_t)rowg * 256 + k0 + q * 8);
            short8 al = *(const short8*)(xlb + (size_t)rowg * 256 + k0 + q * 8);
            short8 bh = *(const short8*)(zhb + (size_t)(ct * 16 + lc) * 256 + k0 + q * 8);
            short8 bl = *(const short8*)(zlb + (size_t)(ct * 16 + lc) * 256 + k0 + q * 8);
            acc = MFMA(ah, bh, acc);
            acc = MFMA(ah, bl, acc);
            acc = MFMA(al, bh, acc);
        }
#pragma unroll
        for (int r = 0; r < 4; r++) S[w * 16 + q * 4 + r][ct * 16 + lc] = acc[r];
    }
    __syncthreads();
    if (tid < 64) {
        float mx = -INFINITY;
        for (int m = 0; m < 49; m++) mx = fmaxf(mx, S[tid][m]);
        float sum = 0.f;
        for (int m = 0; m < 49; m++) { float e = __expf(S[tid][m] - mx); S[tid][m] = e; sum += e; }
        float inv = 1.f / sum;
        for (int m = 0; m < 64; m++) {
            float vv = (m < 49) ? S[tid][m] * inv : 0.f;
            ushort_t hh, ll; split2(vv, hh, ll);
            awh[tid][m] = hh; awl[tid][m] = ll;
        }
    }
    __syncthreads();
    int nw = l >> 2, cg = l & 3;
#pragma unroll
    for (int ct = 0; ct < 16; ct++) {
        floatx4 acc = (floatx4){0.f, 0.f, 0.f, 0.f};
#pragma unroll
        for (int k0 = 0; k0 < 64; k0 += 32) {
            short8 ah = *(const short8*)(&awh[w * 16 + lc][k0 + q * 8]);
            short8 al = *(const short8*)(&awl[w * 16 + lc][k0 + q * 8]);
            short8 bh = *(const short8*)(ghb + (size_t)(ct * 16 + lc) * 64 + k0 + q * 8);
            short8 bl = *(const short8*)(glb + (size_t)(ct * 16 + lc) * 64 + k0 + q * 8);
            acc = MFMA(ah, bh, acc);
            acc = MFMA(ah, bl, acc);
            acc = MFMA(al, bh, acc);
        }
#pragma unroll
        for (int r = 0; r < 4; r++) T[w][q * 4 + r][lc] = acc[r];
        float4 vv = *(const float4*)&T[w][nw][cg * 4];
        int n = n0 + w * 16 + nw;
        if (n < 961) {
            ushort_t h0, l0, h1, l1, h2, l2_, h3, l3;
            split2(vv.x, h0, l0); split2(vv.y, h1, l1);
            split2(vv.z, h2, l2_); split2(vv.w, h3, l3);
            size_t off = ((size_t)b * 992 + n) * 256 + ct * 16 + cg * 4;
            *(ushort4*)(eh + off) = make_ushort4(h0, h1, h2, h3);
            *(ushort4*)(el + off) = make_ushort4(l0, l1, l2_, l3);
        }
    }
}

// ---------------------------------------------------------------------
// fi conv (K=512 concat(emb, xf_g), hi/lo) -> gxT halo hi/lo + gat_nf bf16
// ---------------------------------------------------------------------
__global__ __launch_bounds__(256) void fi_mfma_kernel(
    const ushort_t* __restrict__ Eh, const ushort_t* __restrict__ El,
    const ushort_t* __restrict__ Gh, const ushort_t* __restrict__ Gl,
    const ushort_t* __restrict__ Wh, const ushort_t* __restrict__ Wl,
    const float* __restrict__ sc, const float* __restrict__ sh,
    ushort_t* __restrict__ gxh, ushort_t* __restrict__ gxl,
    ushort_t* __restrict__ gat_nf)
{
    int b = blockIdx.z;
    const ushort_t* Ebh = Eh + (size_t)b * 992 * 256;
    const ushort_t* Ebl = El + (size_t)b * 992 * 256;
    const ushort_t* Gbh = Gh + (size_t)b * 992 * 256;
    const ushort_t* Gbl = Gl + (size_t)b * 992 * 256;
    ushort_t* gxhb = gxh + (size_t)b * 1089 * 256;
    ushort_t* gxlb = gxl + (size_t)b * 1089 * 256;
    ushort_t* gn = gat_nf + (size_t)b * 256 * 992;
    int tid = threadIdx.x, w = tid >> 6, l = tid & 63, lc = l & 15, q = l >> 4;
    int m0 = w * 64, nb0 = blockIdx.x * 32;

    floatx4 acc[4][2];
#pragma unroll
    for (int i = 0; i < 4; i++)
#pragma unroll
        for (int j = 0; j < 2; j++) acc[i][j] = (floatx4){0.f, 0.f, 0.f, 0.f};

    for (int k0 = 0; k0 < 512; k0 += 32) {
        const ushort_t* sh_ = (k0 < 256) ? Ebh : Gbh;
        const ushort_t* sl_ = (k0 < 256) ? Ebl : Gbl;
        int kk = (k0 < 256) ? k0 : k0 - 256;
        short8 ah[4], al[4], bh[2], bl[2];
#pragma unroll
        for (int mt = 0; mt < 4; mt++) {
            size_t off = (size_t)(m0 + mt * 16 + lc) * 512 + k0 + q * 8;
            ah[mt] = *(const short8*)(Wh + off);
            al[mt] = *(const short8*)(Wl + off);
        }
#pragma unroll
        for (int jt = 0; jt < 2; jt++) {
            size_t off = (size_t)(nb0 + jt * 16 + lc) * 256 + kk + q * 8;
            bh[jt] = *(const short8*)(sh_ + off);
            bl[jt] = *(const short8*)(sl_ + off);
        }
#pragma unroll
        for (int mt = 0; mt < 4; mt++)
#pragma unroll
            for (int jt = 0; jt < 2; jt++) {
                acc[mt][jt] = MFMA(ah[mt], bh[jt], acc[mt][jt]);
                acc[mt][jt] = MFMA(ah[mt], bl[jt], acc[mt][jt]);
                acc[mt][jt] = MFMA(al[mt], bh[jt], acc[mt][jt]);
            }
    }
#pragma unroll
    for (int mt = 0; mt < 4; mt++) {
        int mb = m0 + mt * 16 + q * 4;
        float s0 = sc[mb], s1 = sc[mb + 1], s2 = sc[mb + 2], s3 = sc[mb + 3];
        float h0 = sh[mb], h1 = sh[mb + 1], h2 = sh[mb + 2], h3 = sh[mb + 3];
#pragma unroll
        for (int jt = 0; jt < 2; jt++) {
            int n = nb0 + jt * 16 + lc;
            if (n >= 961) continue;
            float v0 = fmaxf(acc[mt][jt][0] * s0 + h0, 0.f);
            float v1 = fmaxf(acc[mt][jt][1] * s1 + h1, 0.f);
            float v2 = fmaxf(acc[mt][jt][2] * s2 + h2, 0.f);
            float v3 = fmaxf(acc[mt][jt][3] * s3 + h3, 0.f);
            ushort_t a0, b0, a1, b1, a2, b2, a3, b3;
            split2(v0, a0, b0); split2(v1, a1, b1); split2(v2, a2, b2); split2(v3, a3, b3);
            int hh = n / 31, ww2 = n - hh * 31;
            int row = (hh + 1) * 33 + (ww2 + 1);
            *(ushort4*)(gxhb + (size_t)row * 256 + mb) = make_ushort4(a0, a1, a2, a3);
            *(ushort4*)(gxlb + (size_t)row * 256 + mb) = make_ushort4(b0, b1, b2, b3);
            gn[(size_t)(mb + 0) * 992 + n] = a0;
            gn[(size_t)(mb + 1) * 992 + n] = a1;
            gn[(size_t)(mb + 2) * 992 + n] = a2;
            gn[(size_t)(mb + 3) * 992 + n] = a3;
        }
    }
}

// ---------------------------------------------------------------------
// conv3x3 split-K: block = 4 waves over ONE 64m x 32j tile; the 72
// (tap,k0) steps are split 18/wave (keeps 24 MFMA / 12 loads ratio of the
// R7 tile), partials reduced through LDS. grid (31,1,32) -> ~15.5 waves/CU.
// ---------------------------------------------------------------------
__global__ __launch_bounds__(256) void conv3x3_mfma_kernel(
    const ushort_t* __restrict__ gxh, const ushort_t* __restrict__ gxl,
    const ushort_t* __restrict__ wmh, const ushort_t* __restrict__ wml,
    const float* __restrict__ sc, const float* __restrict__ sh,
    const float* __restrict__ prelu_a,
    ushort_t* __restrict__ eh, ushort_t* __restrict__ el)
{
    __shared__ float Sp[4][2048];   // 4 waves x (64m x 32j) partials, 32 KB
    int b = blockIdx.z;
    const ushort_t* gxhb = gxh + (size_t)b * 1089 * 256;
    const ushort_t* gxlb = gxl + (size_t)b * 1089 * 256;
    ushort_t* ebh = eh + (size_t)b * 1024 * 64;
    ushort_t* ebl = el + (size_t)b * 1024 * 64;
    int tid = threadIdx.x, w = tid >> 6, l = tid & 63, lc = l & 15, q = l >> 4;
    int j0 = blockIdx.x * 32;

    // per-lane spatial base for the two j-fragments
    int base[2];
#pragma unroll
    for (int jt = 0; jt < 2; jt++) {
        int j = j0 + jt * 16 + lc; if (j > 960) j = 960;
        int hh = j / 31, ww2 = j - hh * 31;
        base[jt] = (hh + 1) * 33 + (ww2 + 1);
    }

    floatx4 acc[4][2];
#pragma unroll
    for (int i = 0; i < 4; i++)
#pragma unroll
        for (int j = 0; j < 2; j++) acc[i][j] = (floatx4){0.f, 0.f, 0.f, 0.f};

    // wave w handles steps [w*18, w*18+18) of 72 = 9 taps x 8 k-chunks
    for (int s = w * 18; s < w * 18 + 18; s++) {
        int tap = s >> 3, k0 = (s & 7) * 32;
        int doff = (tap / 3 - 1) * 33 + (tap % 3 - 1);
        const ushort_t* wth = wmh + tap * 16384;
        const ushort_t* wtl = wml + tap * 16384;
        short8 ah[4], al_[4], bh[2], bl[2];
#pragma unroll
        for (int mt = 0; mt < 4; mt++) {
            size_t off = (size_t)(mt * 16 + lc) * 256 + k0 + q * 8;
            ah[mt]  = *(const short8*)(wth + off);
            al_[mt] = *(const short8*)(wtl + off);
        }
#pragma unroll
        for (int jt = 0; jt < 2; jt++) {
            size_t off = (size_t)(base[jt] + doff) * 256 + k0 + q * 8;
            bh[jt] = *(const short8*)(gxhb + off);
            bl[jt] = *(const short8*)(gxlb + off);
        }
#pragma unroll
        for (int mt = 0; mt < 4; mt++)
#pragma unroll
            for (int jt = 0; jt < 2; jt++) {
                acc[mt][jt] = MFMA(ah[mt], bh[jt], acc[mt][jt]);
                acc[mt][jt] = MFMA(ah[mt], bl[jt], acc[mt][jt]);
                acc[mt][jt] = MFMA(al_[mt], bh[jt], acc[mt][jt]);
            }
    }

    // stage partials: Sp[w][m*32 + j], m = mt*16 + q*4 + r, j = jt*16 + lc
#pragma unroll
    for (int mt = 0; mt < 4; mt++)
#pragma unroll
        for (int jt = 0; jt < 2; jt++)
#pragma unroll
            for (int r = 0; r < 4; r++)
                Sp[w][(mt * 16 + q * 4 + r) * 32 + jt * 16 + lc] = acc[mt][jt][r];
    __syncthreads();

    // reduce + BN + PReLU + split + store. 512 groups of (j, 4m); thread t
    // handles g = t and g = t + 256; j = g & 31 (bank-spread), mg = g >> 5.
    float pa = prelu_a[0];
#pragma unroll
    for (int gi = 0; gi < 2; gi++) {
        int g = tid + gi * 256;
        int j = g & 31, mg = g >> 5;
        int m = mg * 4;
        int jj = j0 + j;
        if (jj >= 961) continue;
        float v[4];
#pragma unroll
        for (int i = 0; i < 4; i++) {
            int idx = (m + i) * 32 + j;
            v[i] = Sp[0][idx] + Sp[1][idx] + Sp[2][idx] + Sp[3][idx];
            v[i] = v[i] * sc[m + i] + sh[m + i];
            v[i] = v[i] >= 0.f ? v[i] : pa * v[i];
        }
        ushort_t a0, b0, a1, b1, a2, b2, a3, b3;
        split2(v[0], a0, b0); split2(v[1], a1, b1);
        split2(v[2], a2, b2); split2(v[3], a3, b3);
        *(ushort4*)(ebh + (size_t)jj * 64 + m) = make_ushort4(a0, a1, a2, a3);
        *(ushort4*)(ebl + (size_t)jj * 64 + m) = make_ushort4(b0, b1, b2, b3);
    }
}

// ---------------------------------------------------------------------
// HSPA: S = e^T e (3-term hi/lo MFMA) -> sparsemax via Michelot/Newton
// ---------------------------------------------------------------------
__global__ __launch_bounds__(512) void hspa_mfma_kernel(
    const ushort_t* __restrict__ eh, const ushort_t* __restrict__ el,
    ushort_t* __restrict__ PT)
{
    const int PITCH = 978;
    __shared__ float S[16 * 978];
    int b = blockIdx.y, nb = blockIdx.x;
    const ushort_t* ebh = eh + (size_t)b * 1024 * 64;
    const ushort_t* ebl = el + (size_t)b * 1024 * 64;
    ushort_t* Pb = PT + (size_t)b * 1024 * 992;
    int tid = threadIdx.x, w = tid >> 6, l = tid & 63, lc = l & 15, q = l >> 4;
    int n0 = nb * 16;

    short8 a0h = *(const short8*)(ebh + (size_t)(n0 + lc) * 64 + q * 8);
    short8 a0l = *(const short8*)(ebl + (size_t)(n0 + lc) * 64 + q * 8);
    short8 a1h = *(const short8*)(ebh + (size_t)(n0 + lc) * 64 + 32 + q * 8);
    short8 a1l = *(const short8*)(ebl + (size_t)(n0 + lc) * 64 + 32 + q * 8);

    for (int jt = w; jt < 61; jt += 8) {
        int j = jt * 16 + lc;
        short8 b0h = *(const short8*)(ebh + (size_t)j * 64 + q * 8);
        short8 b0l = *(const short8*)(ebl + (size_t)j * 64 + q * 8);
        short8 b1h = *(const short8*)(ebh + (size_t)j * 64 + 32 + q * 8);
        short8 b1l = *(const short8*)(ebl + (size_t)j * 64 + 32 + q * 8);
        floatx4 acc = (floatx4){0.f, 0.f, 0.f, 0.f};
        acc = MFMA(a0h, b0h, acc);
        acc = MFMA(a0h, b0l, acc);
        acc = MFMA(a0l, b0h, acc);
        acc = MFMA(a1h, b1h, acc);
        acc = MFMA(a1h, b1l, acc);
        acc = MFMA(a1l, b1h, acc);
#pragma unroll
        for (int r = 0; r < 4; r++) S[(q * 4 + r) * PITCH + j] = acc[r];
    }
    __syncthreads();

    int r0 = w * 2, r1 = w * 2 + 1;
    float sv0[16], sv1[16];
    float mx0 = -INFINITY, mx1 = -INFINITY;
#pragma unroll
    for (int t = 0; t < 16; t++) {
        int j = l + t * 64;
        float s0 = (j < 961) ? S[r0 * PITCH + j] : -INFINITY;
        float s1 = (j < 961) ? S[r1 * PITCH + j] : -INFINITY;
        sv0[t] = s0; sv1[t] = s1;
        mx0 = fmaxf(mx0, s0); mx1 = fmaxf(mx1, s1);
    }
    for (int off = 32; off; off >>= 1) {
        mx0 = fmaxf(mx0, __shfl_xor(mx0, off));
        mx1 = fmaxf(mx1, __shfl_xor(mx1, off));
    }
#pragma unroll
    for (int t = 0; t < 16; t++) { sv0[t] -= mx0; sv1[t] -= mx1; }

    float tau0 = -1.f, tau1 = -1.f;
    for (int it = 0; it < 16; it++) {
        float s0 = 0.f, c0 = 0.f, s1 = 0.f, c1 = 0.f;
#pragma unroll
        for (int t = 0; t < 16; t++) {
            if (sv0[t] > tau0) { s0 += sv0[t]; c0 += 1.f; }
            if (sv1[t] > tau1) { s1 += sv1[t]; c1 += 1.f; }
        }
        for (int off = 32; off; off >>= 1) {
            s0 += __shfl_xor(s0, off); c0 += __shfl_xor(c0, off);
            s1 += __shfl_xor(s1, off); c1 += __shfl_xor(c1, off);
        }
        float nt0 = (s0 - 1.f) / c0;
        float nt1 = (s1 - 1.f) / c1;
        bool conv = (nt0 == tau0) && (nt1 == tau1);
        tau0 = nt0; tau1 = nt1;
        if (conv) break;
    }
#pragma unroll
    for (int t = 0; t < 16; t++) {
        int j = l + t * 64;
        if (j < 976) {
            S[r0 * PITCH + j] = (j < 961) ? fmaxf(sv0[t] - tau0, 0.f) : 0.f;
            S[r1 * PITCH + j] = (j < 961) ? fmaxf(sv1[t] - tau1, 0.f) : 0.f;
        }
    }
    __syncthreads();

    for (int j = tid; j < 976; j += 512) {
        union { ushort_t u[8]; uint4 v; } p0, p1;
#pragma unroll
        for (int r = 0; r < 8; r++)  p0.u[r] = f2bf(S[r * PITCH + j]);
#pragma unroll
        for (int r = 0; r < 8; r++)  p1.u[r] = f2bf(S[(8 + r) * PITCH + j]);
        ushort_t* dst = Pb + (size_t)j * 992 + n0;
        *(uint4*)(dst) = p0.v;
        *(uint4*)(dst + 8) = p1.v;
    }
}

// ---------------------------------------------------------------------
// out = gat @ P + gat. Single bf16 MFMA (incoherent noise OK).
// ---------------------------------------------------------------------
__global__ __launch_bounds__(256) void out_mfma_kernel(
    const ushort_t* __restrict__ gat_nf, const ushort_t* __restrict__ PT,
    float* __restrict__ out)
{
    int b = blockIdx.z, jb = blockIdx.x;
    const ushort_t* gb = gat_nf + (size_t)b * 256 * 992;
    const ushort_t* Pb = PT + (size_t)b * 1024 * 992;
    float* ob = out + (size_t)b * 256 * 961;
    int tid = threadIdx.x, w = tid >> 6, l = tid & 63, lc = l & 15, q = l >> 4;
    int m0 = w * 64, j0 = jb * 64;

    floatx4 acc[4][4];
#pragma unroll
    for (int i = 0; i < 4; i++)
#pragma unroll
        for (int j = 0; j < 4; j++) acc[i][j] = (floatx4){0.f, 0.f, 0.f, 0.f};

    for (int k0 = 0; k0 < 992; k0 += 32) {
        short8 a[4], bb[4];
#pragma unroll
        for (int mt = 0; mt < 4; mt++)
            a[mt] = *(const short8*)(gb + (size_t)(m0 + mt * 16 + lc) * 992 + k0 + q * 8);
#pragma unroll
        for (int jt = 0; jt < 4; jt++)
            bb[jt] = *(const short8*)(Pb + (size_t)(j0 + jt * 16 + lc) * 992 + k0 + q * 8);
#pragma unroll
        for (int mt = 0; mt < 4; mt++)
#pragma unroll
            for (int jt = 0; jt < 4; jt++)
                acc[mt][jt] = MFMA(a[mt], bb[jt], acc[mt][jt]);
    }
#pragma unroll
    for (int mt = 0; mt < 4; mt++) {
        int mb = m0 + mt * 16 + q * 4;
#pragma unroll
        for (int jt = 0; jt < 4; jt++) {
            int j = j0 + jt * 16 + lc;
            if (j >= 961) continue;
#pragma unroll
            for (int r = 0; r < 4; r++) {
                float g = bf2f(gb[(size_t)(mb + r) * 992 + j]);
                ob[(size_t)(mb + r) * 961 + j] = acc[mt][jt][r] + g;
            }
        }
    }
}

// =====================================================================
extern "C" void kernel_launch(void* const* d_in, const int* in_sizes, int n_in,
                              void* d_out, int out_size, void* d_ws, size_t ws_size,
                              hipStream_t stream)
{
    const float* zf      = (const float*)d_in[0];
    const float* xf      = (const float*)d_in[1];
    const float* Wq      = (const float*)d_in[2];
    const float* bq      = (const float*)d_in[3];
    const float* Ws      = (const float*)d_in[4];
    const float* bs      = (const float*)d_in[5];
    const float* Wg      = (const float*)d_in[6];
    const float* bg      = (const float*)d_in[7];
    const float* g_gamma = (const float*)d_in[8];
    const float* g_beta  = (const float*)d_in[9];
    const float* g_mean  = (const float*)d_in[10];
    const float* g_var   = (const float*)d_in[11];
    const float* Wfi     = (const float*)d_in[12];
    const float* bfi     = (const float*)d_in[13];
    const float* fi_gamma= (const float*)d_in[14];
    const float* fi_beta = (const float*)d_in[15];
    const float* fi_mean = (const float*)d_in[16];
    const float* fi_var  = (const float*)d_in[17];
    const float* Wm      = (const float*)d_in[18];
    const float* bm      = (const float*)d_in[19];
    const float* m_gamma = (const float*)d_in[20];
    const float* m_beta  = (const float*)d_in[21];
    const float* m_mean  = (const float*)d_in[22];
    const float* m_var   = (const float*)d_in[23];
    const float* prelu_a = (const float*)d_in[24];
    float* out = (float*)d_out;

    ushort_t* ws = (ushort_t*)d_ws;
    ushort_t* Wq_h  = ws + 0;         ushort_t* Wq_l  = ws + 65536;
    ushort_t* Ws_h  = ws + 131072;    ushort_t* Ws_l  = ws + 196608;
    ushort_t* Wg_h  = ws + 262144;    ushort_t* Wg_l  = ws + 327680;
    ushort_t* Wfi_h = ws + 393216;    ushort_t* Wfi_l = ws + 524288;
    ushort_t* wm_h  = ws + 655360;    ushort_t* wm_l  = ws + 802816;
    ushort_t* XT_h    = ws + 950272;      // 8,126,464 each
    ushort_t* XT_l    = ws + 9076736;
    ushort_t* xf_tT_h = ws + 17203200;
    ushort_t* xf_tT_l = ws + 25329664;
    ushort_t* zf_tT_h = ws + 33456128;    // 524,288 each
    ushort_t* zf_tT_l = ws + 33980416;
    ushort_t* zf_gT_h = ws + 34504704;
    ushort_t* zf_gT_l = ws + 35028992;
    ushort_t* gxT_h   = ws + 17203200;    // aliases xf_tT region (dead after attn)
    ushort_t* gxT_l   = ws + 26124288;
    ushort_t* xf_gT_h = ws + 35553280;
    ushort_t* xf_gT_l = ws + 43679744;
    ushort_t* gat_nf  = ws + 51806208;    // 8,126,464
    ushort_t* eT_h    = ws + 59932672;    // 2,097,152 each
    ushort_t* eT_l    = ws + 62029824;
    ushort_t* PT      = ws + 64126976;    // 32,505,856
    ushort_t* zfT_h   = ws + 96632832;    // 524,288 each
    ushort_t* zfT_l   = ws + 97157120;
    float* scsh       = (float*)(ws + 97681408);   // 2176 floats
    ushort_t* zgC_h   = ws + 97685760;    // 524,288 each
    ushort_t* zgC_l   = ws + 98210048;
    ushort_t* embT_h = XT_h;
    ushort_t* embT_l = XT_l;

    const float* sc_q  = scsh + 0,    *sh_q  = scsh + 256;
    const float* sc_s  = scsh + 512,  *sh_s  = scsh + 768;
    const float* sc_g  = scsh + 1024, *sh_g  = scsh + 1280;
    const float* sc_fi = scsh + 1536, *sh_fi = scsh + 1792;
    const float* sc_m  = scsh + 2048, *sh_m  = scsh + 2112;

    prep_all_kernel<<<1857, 256, 0, stream>>>(
        Wq, Ws, Wg, Wfi, Wm,
        bq, bs, bg, g_gamma, g_beta, g_mean, g_var,
        bfi, fi_gamma, fi_beta, fi_mean, fi_var,
        bm, m_gamma, m_beta, m_mean, m_var,
        Wq_h, Wq_l, Ws_h, Ws_l, Wg_h, Wg_l, Wfi_h, Wfi_l, wm_h, wm_l, scsh);

    transpose_in_kernel<<<dim3(31, 8, 32), 256, 0, stream>>>(xf, XT_h, XT_l, 961, 992);
    transpose_in_kernel<<<dim3(2, 8, 32), 256, 0, stream>>>(zf, zfT_h, zfT_l, 49, 64);

    dualconv_mfma_kernel<<<dim3(31, 1, 32), 512, 0, stream>>>(
        XT_h, XT_l, Wq_h, Wq_l, Wg_h, Wg_l,
        sc_q, sh_q, sc_g, sh_g, 0, 1,
        xf_tT_h, xf_tT_l, xf_gT_h, xf_gT_l,
        nullptr, nullptr, 0, 256, 961, 992, 992);
    dualconv_mfma_kernel<<<dim3(2, 1, 32), 512, 0, stream>>>(
        zfT_h, zfT_l, Ws_h, Ws_l, Wg_h, Wg_l,
        sc_s, sh_s, sc_g, sh_g, 0, 1,
        zf_tT_h, zf_tT_l, zf_gT_h, zf_gT_l,
        zgC_h, zgC_l, 64, 256, 49, 64, 64);

    attn_mfma_kernel<<<dim3(16, 32), 256, 0, stream>>>(
        xf_tT_h, xf_tT_l, zf_tT_h, zf_tT_l, zgC_h, zgC_l, embT_h, embT_l);

    halo_zero_kernel<<<16, 256, 0, stream>>>(gxT_h, gxT_l);

    fi_mfma_kernel<<<dim3(31, 1, 32), 256, 0, stream>>>(
        embT_h, embT_l, xf_gT_h, xf_gT_l, Wfi_h, Wfi_l, sc_fi, sh_fi,
        gxT_h, gxT_l, gat_nf);

    conv3x3_mfma_kernel<<<dim3(31, 1, 32), 256, 0, stream>>>(
        gxT_h, gxT_l, wm_h, wm_l, sc_m, sh_m, prelu_a, eT_h, eT_l);

    hspa_mfma_kernel<<<dim3(61, 32), 512, 0, stream>>>(eT_h, eT_l, PT);

    out_mfma_kernel<<<dim3(16, 1, 32), 256, 0, stream>>>(gat_nf, PT, out);
}

// Round 10
// 661.871 us; speedup vs baseline: 1.1547x; 1.0201x over previous
//
#include <hip/hip_runtime.h>
#include <cstdint>
#include <cstddef>
#include <math.h>

typedef __attribute__((ext_vector_type(8))) short short8;
typedef __attribute__((ext_vector_type(4))) float floatx4;
typedef unsigned short ushort_t;

__device__ __forceinline__ ushort_t f2bf(float x) {
    union { float f; unsigned u; } v; v.f = x;
    unsigned r = v.u + 0x7FFF + ((v.u >> 16) & 1);
    return (ushort_t)(r >> 16);
}
__device__ __forceinline__ float bf2f(ushort_t h) {
    union { unsigned u; float f; } v; v.u = ((unsigned)h) << 16; return v.f;
}
__device__ __forceinline__ void split2(float v, ushort_t& h, ushort_t& l) {
    h = f2bf(v);
    l = f2bf(v - bf2f(h));
}

#define MFMA(a, b, c) __builtin_amdgcn_mfma_f32_16x16x32_bf16((a), (b), (c), 0, 0, 0)

// ---------------------------------------------------------------------
// prep_all: all weight hi/lo splits + Wm transpose + BN fold, one launch.
// ---------------------------------------------------------------------
__global__ void prep_all_kernel(
    const float* __restrict__ Wq, const float* __restrict__ Ws,
    const float* __restrict__ Wg, const float* __restrict__ Wfi,
    const float* __restrict__ Wm,
    const float* bq, const float* bs,
    const float* bg, const float* gg, const float* gb, const float* gm, const float* gv,
    const float* bfi, const float* fg, const float* fb, const float* fm, const float* fv,
    const float* bm, const float* mg, const float* mb, const float* mm, const float* mv,
    ushort_t* Wq_h, ushort_t* Wq_l, ushort_t* Ws_h, ushort_t* Ws_l,
    ushort_t* Wg_h, ushort_t* Wg_l, ushort_t* Wfi_h, ushort_t* Wfi_l,
    ushort_t* wm_h, ushort_t* wm_l, float* scsh)
{
    int bid = blockIdx.x, t = threadIdx.x;
    if (bid < 256) {
        int i = bid * 256 + t; ushort_t h, l; split2(Wq[i], h, l); Wq_h[i] = h; Wq_l[i] = l;
    } else if (bid < 512) {
        int i = (bid - 256) * 256 + t; ushort_t h, l; split2(Ws[i], h, l); Ws_h[i] = h; Ws_l[i] = l;
    } else if (bid < 768) {
        int i = (bid - 512) * 256 + t; ushort_t h, l; split2(Wg[i], h, l); Wg_h[i] = h; Wg_l[i] = l;
    } else if (bid < 1280) {
        int i = (bid - 768) * 256 + t; ushort_t h, l; split2(Wfi[i], h, l); Wfi_h[i] = h; Wfi_l[i] = l;
    } else if (bid < 1856) {
        int i = (bid - 1280) * 256 + t;  // [tap][m][c] flattened
        int c = i & 255, m = (i >> 8) & 63, tap = i >> 14;
        ushort_t h, l; split2(Wm[((size_t)m * 256 + c) * 9 + tap], h, l);
        wm_h[i] = h; wm_l[i] = l;
    } else {
        if (t < 256) {
            scsh[t] = 1.f;        scsh[256 + t] = bq[t];
            scsh[512 + t] = 1.f;  scsh[768 + t] = bs[t];
            float s = gg[t] * rsqrtf(gv[t] + 1e-5f);
            scsh[1024 + t] = s;   scsh[1280 + t] = gb[t] + s * (bg[t] - gm[t]);
            float s2 = fg[t] * rsqrtf(fv[t] + 1e-5f);
            scsh[1536 + t] = s2;  scsh[1792 + t] = fb[t] + s2 * (bfi[t] - fm[t]);
            if (t < 64) {
                float s3 = mg[t] * rsqrtf(mv[t] + 1e-5f);
                scsh[2048 + t] = s3; scsh[2112 + t] = mb[t] + s3 * (bm[t] - mm[t]);
            }
        }
    }
}

// halo-only zero of gxT (128 halo rows per batch, hi+lo)
__global__ void halo_zero_kernel(ushort_t* __restrict__ gxh, ushort_t* __restrict__ gxl) {
    int i = blockIdx.x * 256 + threadIdx.x;   // 0..4095
    int b = i >> 7, k = i & 127;
    int r;
    if (k < 33) r = k;
    else if (k < 66) r = 32 * 33 + (k - 33);
    else { int k2 = k - 66; r = ((k2 >> 1) + 1) * 33 + ((k2 & 1) ? 32 : 0); }
    uint4* ph = (uint4*)(gxh + ((size_t)b * 1089 + r) * 256);
    uint4* pl = (uint4*)(gxl + ((size_t)b * 1089 + r) * 256);
    uint4 z = make_uint4(0, 0, 0, 0);
#pragma unroll
    for (int s = 0; s < 32; s++) { ph[s] = z; pl[s] = z; }
}

// fp32 [B][256][Nsrc] -> bf16 hi/lo [B][Npad][256]
__global__ __launch_bounds__(256) void transpose_in_kernel(
    const float* __restrict__ in, ushort_t* __restrict__ oh, ushort_t* __restrict__ ol,
    int Nsrc, int Npad)
{
    int b = blockIdx.z;
    const float* ib = in + (size_t)b * 256 * Nsrc;
    ushort_t* obh = oh + (size_t)b * Npad * 256;
    ushort_t* obl = ol + (size_t)b * Npad * 256;
    __shared__ float tile[32][33];
    int n0 = blockIdx.x * 32, c0 = blockIdx.y * 32;
    int tx = threadIdx.x & 31, ty = threadIdx.x >> 5;
#pragma unroll
    for (int r = 0; r < 4; r++) {
        int c = c0 + ty + r * 8, n = n0 + tx;
        tile[ty + r * 8][tx] = (n < Nsrc) ? ib[(size_t)c * Nsrc + n] : 0.f;
    }
    __syncthreads();
#pragma unroll
    for (int r = 0; r < 4; r++) {
        int n = n0 + ty + r * 8, c = c0 + tx;
        if (n < Nsrc) {
            ushort_t h, l; split2(tile[tx][ty + r * 8], h, l);
            obh[(size_t)n * 256 + c] = h;
            obl[(size_t)n * 256 + c] = l;
        }
    }
}

// ---------------------------------------------------------------------
// dual conv1x1: O1 = act1(W1@X), O2 = act2(W2@X) sharing X B-tiles.
// grid (B, ntiles) — batch-major for XCD L2 locality.
// ---------------------------------------------------------------------
__global__ __launch_bounds__(512) void dualconv_mfma_kernel(
    const ushort_t* __restrict__ Xh, const ushort_t* __restrict__ Xl,
    const ushort_t* __restrict__ W1h, const ushort_t* __restrict__ W1l,
    const ushort_t* __restrict__ W2h, const ushort_t* __restrict__ W2l,
    const float* __restrict__ sc1, const float* __restrict__ sh1,
    const float* __restrict__ sc2, const float* __restrict__ sh2,
    int relu1, int relu2,
    ushort_t* __restrict__ O1h, ushort_t* __restrict__ O1l,
    ushort_t* __restrict__ O2h, ushort_t* __restrict__ O2l,
    ushort_t* __restrict__ O2ch, ushort_t* __restrict__ O2cl, int cpitch,
    int K, int Nvalid, int NpadIn, int NpadOut)
{
    int b = blockIdx.x;
    const ushort_t* Xbh = Xh + (size_t)b * NpadIn * K;
    const ushort_t* Xbl = Xl + (size_t)b * NpadIn * K;
    int tid = threadIdx.x, w = tid >> 6, l = tid & 63, lc = l & 15, q = l >> 4;
    int half = w >> 2;
    int m0 = (w & 3) * 64, nb0 = blockIdx.y * 32;

    const ushort_t* Wh = half ? W2h : W1h;
    const ushort_t* Wl = half ? W2l : W1l;
    const float* sc = half ? sc2 : sc1;
    const float* sh = half ? sh2 : sh1;
    int relu = half ? relu2 : relu1;
    ushort_t* Obh = (half ? O2h : O1h) + (size_t)b * NpadOut * 256;
    ushort_t* Obl = (half ? O2l : O1l) + (size_t)b * NpadOut * 256;

    floatx4 acc[4][2];
#pragma unroll
    for (int i = 0; i < 4; i++)
#pragma unroll
        for (int j = 0; j < 2; j++) acc[i][j] = (floatx4){0.f, 0.f, 0.f, 0.f};

    for (int k0 = 0; k0 < K; k0 += 32) {
        short8 ah[4], al[4], bh[2], bl[2];
#pragma unroll
        for (int mt = 0; mt < 4; mt++) {
            size_t off = (size_t)(m0 + mt * 16 + lc) * K + k0 + q * 8;
            ah[mt] = *(const short8*)(Wh + off);
            al[mt] = *(const short8*)(Wl + off);
        }
#pragma unroll
        for (int jt = 0; jt < 2; jt++) {
            size_t off = (size_t)(nb0 + jt * 16 + lc) * K + k0 + q * 8;
            bh[jt] = *(const short8*)(Xbh + off);
            bl[jt] = *(const short8*)(Xbl + off);
        }
#pragma unroll
        for (int mt = 0; mt < 4; mt++)
#pragma unroll
            for (int jt = 0; jt < 2; jt++) {
                acc[mt][jt] = MFMA(ah[mt], bh[jt], acc[mt][jt]);
                acc[mt][jt] = MFMA(ah[mt], bl[jt], acc[mt][jt]);
                acc[mt][jt] = MFMA(al[mt], bh[jt], acc[mt][jt]);
            }
    }
#pragma unroll
    for (int mt = 0; mt < 4; mt++) {
        int mb = m0 + mt * 16 + q * 4;
        float s0 = sc[mb], s1 = sc[mb + 1], s2 = sc[mb + 2], s3 = sc[mb + 3];
        float h0 = sh[mb], h1 = sh[mb + 1], h2 = sh[mb + 2], h3 = sh[mb + 3];
#pragma unroll
        for (int jt = 0; jt < 2; jt++) {
            int n = nb0 + jt * 16 + lc;
            if (n >= Nvalid) continue;
            float v0 = acc[mt][jt][0] * s0 + h0;
            float v1 = acc[mt][jt][1] * s1 + h1;
            float v2 = acc[mt][jt][2] * s2 + h2;
            float v3 = acc[mt][jt][3] * s3 + h3;
            if (relu) { v0 = fmaxf(v0, 0.f); v1 = fmaxf(v1, 0.f); v2 = fmaxf(v2, 0.f); v3 = fmaxf(v3, 0.f); }
            ushort_t e0, f0, e1, f1, e2, f2, e3, f3;
            split2(v0, e0, f0); split2(v1, e1, f1); split2(v2, e2, f2); split2(v3, e3, f3);
            *(ushort4*)(Obh + (size_t)n * 256 + mb) = make_ushort4(e0, e1, e2, e3);
            *(ushort4*)(Obl + (size_t)n * 256 + mb) = make_ushort4(f0, f1, f2, f3);
            if (half && O2ch) {
                O2ch[((size_t)b * 256 + mb + 0) * cpitch + n] = e0;
                O2ch[((size_t)b * 256 + mb + 1) * cpitch + n] = e1;
                O2ch[((size_t)b * 256 + mb + 2) * cpitch + n] = e2;
                O2ch[((size_t)b * 256 + mb + 3) * cpitch + n] = e3;
                O2cl[((size_t)b * 256 + mb + 0) * cpitch + n] = f0;
                O2cl[((size_t)b * 256 + mb + 1) * cpitch + n] = f1;
                O2cl[((size_t)b * 256 + mb + 2) * cpitch + n] = f2;
                O2cl[((size_t)b * 256 + mb + 3) * cpitch + n] = f3;
            }
        }
    }
}

// ---------------------------------------------------------------------
// attention via MFMA: sim GEMM -> fp32 softmax -> emb GEMM. grid (B, 16).
// ---------------------------------------------------------------------
__global__ __launch_bounds__(256) void attn_mfma_kernel(
    const ushort_t* __restrict__ xth, const ushort_t* __restrict__ xtl,
    const ushort_t* __restrict__ zth, const ushort_t* __restrict__ ztl,
    const ushort_t* __restrict__ zgh, const ushort_t* __restrict__ zgl,
    ushort_t* __restrict__ eh, ushort_t* __restrict__ el)
{
    __shared__ float S[64][68];
    __shared__ ushort_t awh[64][72], awl[64][72];
    __shared__ float T[4][16][20];
    int b = blockIdx.x, n0 = blockIdx.y * 64;
    int tid = threadIdx.x, w = tid >> 6, l = tid & 63, lc = l & 15, q = l >> 4;
    const ushort_t* xhb = xth + (size_t)b * 992 * 256;
    const ushort_t* xlb = xtl + (size_t)b * 992 * 256;
    const ushort_t* zhb = zth + (size_t)b * 64 * 256;
    const ushort_t* zlb = ztl + (size_t)b * 64 * 256;
    const ushort_t* ghb = zgh + (size_t)b * 256 * 64;
    const ushort_t* glb = zgl + (size_t)b * 256 * 64;

    int rowg = n0 + w * 16 + lc;
#pragma unroll
    for (int ct = 0; ct < 4; ct++) {
        floatx4 acc = (floatx4){0.f, 0.f, 0.f, 0.f};
        for (int k0 = 0; k0 < 256; k0 += 32) {
            short8 ah = *(const short8*)(xhb + (size_t)rowg * 256 + k0 + q * 8);
            short8 al = *(const short8*)(xlb + (size_t)rowg * 256 + k0 + q * 8);
            short8 bh = *(const short8*)(zhb + (size_t)(ct * 16 + lc) * 256 + k0 + q * 8);
            short8 bl = *(const short8*)(zlb + (size_t)(ct * 16 + lc) * 256 + k0 + q * 8);
            acc = MFMA(ah, bh, acc);
            acc = MFMA(ah, bl, acc);
            acc = MFMA(al, bh, acc);
        }
#pragma unroll
        for (int r = 0; r < 4; r++) S[w * 16 + q * 4 + r][ct * 16 + lc] = acc[r];
    }
    __syncthreads();
    if (tid < 64) {
        float mx = -INFINITY;
        for (int m = 0; m < 49; m++) mx = fmaxf(mx, S[tid][m]);
        float sum = 0.f;
        for (int m = 0; m < 49; m++) { float e = __expf(S[tid][m] - mx); S[tid][m] = e; sum += e; }
        float inv = 1.f / sum;
        for (int m = 0; m < 64; m++) {
            float vv = (m < 49) ? S[tid][m] * inv : 0.f;
            ushort_t hh, ll; split2(vv, hh, ll);
            awh[tid][m] = hh; awl[tid][m] = ll;
        }
    }
    __syncthreads();
    int nw = l >> 2, cg = l & 3;
#pragma unroll
    for (int ct = 0; ct < 16; ct++) {
        floatx4 acc = (floatx4){0.f, 0.f, 0.f, 0.f};
#pragma unroll
        for (int k0 = 0; k0 < 64; k0 += 32) {
            short8 ah = *(const short8*)(&awh[w * 16 + lc][k0 + q * 8]);
            short8 al = *(const short8*)(&awl[w * 16 + lc][k0 + q * 8]);
            short8 bh = *(const short8*)(ghb + (size_t)(ct * 16 + lc) * 64 + k0 + q * 8);
            short8 bl = *(const short8*)(glb + (size_t)(ct * 16 + lc) * 64 + k0 + q * 8);
            acc = MFMA(ah, bh, acc);
            acc = MFMA(ah, bl, acc);
            acc = MFMA(al, bh, acc);
        }
#pragma unroll
        for (int r = 0; r < 4; r++) T[w][q * 4 + r][lc] = acc[r];
        float4 vv = *(const float4*)&T[w][nw][cg * 4];
        int n = n0 + w * 16 + nw;
        if (n < 961) {
            ushort_t h0, l0, h1, l1, h2, l2_, h3, l3;
            split2(vv.x, h0, l0); split2(vv.y, h1, l1);
            split2(vv.z, h2, l2_); split2(vv.w, h3, l3);
            size_t off = ((size_t)b * 992 + n) * 256 + ct * 16 + cg * 4;
            *(ushort4*)(eh + off) = make_ushort4(h0, h1, h2, h3);
            *(ushort4*)(el + off) = make_ushort4(l0, l1, l2_, l3);
        }
    }
}

// ---------------------------------------------------------------------
// fi conv (K=512 concat(emb, xf_g), hi/lo). grid (B, 31).
// ---------------------------------------------------------------------
__global__ __launch_bounds__(256) void fi_mfma_kernel(
    const ushort_t* __restrict__ Eh, const ushort_t* __restrict__ El,
    const ushort_t* __restrict__ Gh, const ushort_t* __restrict__ Gl,
    const ushort_t* __restrict__ Wh, const ushort_t* __restrict__ Wl,
    const float* __restrict__ sc, const float* __restrict__ sh,
    ushort_t* __restrict__ gxh, ushort_t* __restrict__ gxl,
    ushort_t* __restrict__ gat_nf)
{
    int b = blockIdx.x;
    const ushort_t* Ebh = Eh + (size_t)b * 992 * 256;
    const ushort_t* Ebl = El + (size_t)b * 992 * 256;
    const ushort_t* Gbh = Gh + (size_t)b * 992 * 256;
    const ushort_t* Gbl = Gl + (size_t)b * 992 * 256;
    ushort_t* gxhb = gxh + (size_t)b * 1089 * 256;
    ushort_t* gxlb = gxl + (size_t)b * 1089 * 256;
    ushort_t* gn = gat_nf + (size_t)b * 256 * 992;
    int tid = threadIdx.x, w = tid >> 6, l = tid & 63, lc = l & 15, q = l >> 4;
    int m0 = w * 64, nb0 = blockIdx.y * 32;

    floatx4 acc[4][2];
#pragma unroll
    for (int i = 0; i < 4; i++)
#pragma unroll
        for (int j = 0; j < 2; j++) acc[i][j] = (floatx4){0.f, 0.f, 0.f, 0.f};

    for (int k0 = 0; k0 < 512; k0 += 32) {
        const ushort_t* sh_ = (k0 < 256) ? Ebh : Gbh;
        const ushort_t* sl_ = (k0 < 256) ? Ebl : Gbl;
        int kk = (k0 < 256) ? k0 : k0 - 256;
        short8 ah[4], al[4], bh[2], bl[2];
#pragma unroll
        for (int mt = 0; mt < 4; mt++) {
            size_t off = (size_t)(m0 + mt * 16 + lc) * 512 + k0 + q * 8;
            ah[mt] = *(const short8*)(Wh + off);
            al[mt] = *(const short8*)(Wl + off);
        }
#pragma unroll
        for (int jt = 0; jt < 2; jt++) {
            size_t off = (size_t)(nb0 + jt * 16 + lc) * 256 + kk + q * 8;
            bh[jt] = *(const short8*)(sh_ + off);
            bl[jt] = *(const short8*)(sl_ + off);
        }
#pragma unroll
        for (int mt = 0; mt < 4; mt++)
#pragma unroll
            for (int jt = 0; jt < 2; jt++) {
                acc[mt][jt] = MFMA(ah[mt], bh[jt], acc[mt][jt]);
                acc[mt][jt] = MFMA(ah[mt], bl[jt], acc[mt][jt]);
                acc[mt][jt] = MFMA(al[mt], bh[jt], acc[mt][jt]);
            }
    }
#pragma unroll
    for (int mt = 0; mt < 4; mt++) {
        int mb = m0 + mt * 16 + q * 4;
        float s0 = sc[mb], s1 = sc[mb + 1], s2 = sc[mb + 2], s3 = sc[mb + 3];
        float h0 = sh[mb], h1 = sh[mb + 1], h2 = sh[mb + 2], h3 = sh[mb + 3];
#pragma unroll
        for (int jt = 0; jt < 2; jt++) {
            int n = nb0 + jt * 16 + lc;
            if (n >= 961) continue;
            float v0 = fmaxf(acc[mt][jt][0] * s0 + h0, 0.f);
            float v1 = fmaxf(acc[mt][jt][1] * s1 + h1, 0.f);
            float v2 = fmaxf(acc[mt][jt][2] * s2 + h2, 0.f);
            float v3 = fmaxf(acc[mt][jt][3] * s3 + h3, 0.f);
            ushort_t a0, b0, a1, b1, a2, b2, a3, b3;
            split2(v0, a0, b0); split2(v1, a1, b1); split2(v2, a2, b2); split2(v3, a3, b3);
            int hh = n / 31, ww2 = n - hh * 31;
            int row = (hh + 1) * 33 + (ww2 + 1);
            *(ushort4*)(gxhb + (size_t)row * 256 + mb) = make_ushort4(a0, a1, a2, a3);
            *(ushort4*)(gxlb + (size_t)row * 256 + mb) = make_ushort4(b0, b1, b2, b3);
            gn[(size_t)(mb + 0) * 992 + n] = a0;
            gn[(size_t)(mb + 1) * 992 + n] = a1;
            gn[(size_t)(mb + 2) * 992 + n] = a2;
            gn[(size_t)(mb + 3) * 992 + n] = a3;
        }
    }
}

// ---------------------------------------------------------------------
// conv3x3 split-K: block = 4 waves over ONE 64m x 32j tile, 72 (tap,k0)
// steps split 18/wave, partials reduced in LDS. grid (B, 31) batch-major.
// ---------------------------------------------------------------------
__global__ __launch_bounds__(256) void conv3x3_mfma_kernel(
    const ushort_t* __restrict__ gxh, const ushort_t* __restrict__ gxl,
    const ushort_t* __restrict__ wmh, const ushort_t* __restrict__ wml,
    const float* __restrict__ sc, const float* __restrict__ sh,
    const float* __restrict__ prelu_a,
    ushort_t* __restrict__ eh, ushort_t* __restrict__ el)
{
    __shared__ float Sp[4][2048];   // 4 waves x (64m x 32j) partials, 32 KB
    int b = blockIdx.x;
    const ushort_t* gxhb = gxh + (size_t)b * 1089 * 256;
    const ushort_t* gxlb = gxl + (size_t)b * 1089 * 256;
    ushort_t* ebh = eh + (size_t)b * 1024 * 64;
    ushort_t* ebl = el + (size_t)b * 1024 * 64;
    int tid = threadIdx.x, w = tid >> 6, l = tid & 63, lc = l & 15, q = l >> 4;
    int j0 = blockIdx.y * 32;

    int base[2];
#pragma unroll
    for (int jt = 0; jt < 2; jt++) {
        int j = j0 + jt * 16 + lc; if (j > 960) j = 960;
        int hh = j / 31, ww2 = j - hh * 31;
        base[jt] = (hh + 1) * 33 + (ww2 + 1);
    }

    floatx4 acc[4][2];
#pragma unroll
    for (int i = 0; i < 4; i++)
#pragma unroll
        for (int j = 0; j < 2; j++) acc[i][j] = (floatx4){0.f, 0.f, 0.f, 0.f};

    for (int s = w * 18; s < w * 18 + 18; s++) {
        int tap = s >> 3, k0 = (s & 7) * 32;
        int doff = (tap / 3 - 1) * 33 + (tap % 3 - 1);
        const ushort_t* wth = wmh + tap * 16384;
        const ushort_t* wtl = wml + tap * 16384;
        short8 ah[4], al_[4], bh[2], bl[2];
#pragma unroll
        for (int mt = 0; mt < 4; mt++) {
            size_t off = (size_t)(mt * 16 + lc) * 256 + k0 + q * 8;
            ah[mt]  = *(const short8*)(wth + off);
            al_[mt] = *(const short8*)(wtl + off);
        }
#pragma unroll
        for (int jt = 0; jt < 2; jt++) {
            size_t off = (size_t)(base[jt] + doff) * 256 + k0 + q * 8;
            bh[jt] = *(const short8*)(gxhb + off);
            bl[jt] = *(const short8*)(gxlb + off);
        }
#pragma unroll
        for (int mt = 0; mt < 4; mt++)
#pragma unroll
            for (int jt = 0; jt < 2; jt++) {
                acc[mt][jt] = MFMA(ah[mt], bh[jt], acc[mt][jt]);
                acc[mt][jt] = MFMA(ah[mt], bl[jt], acc[mt][jt]);
                acc[mt][jt] = MFMA(al_[mt], bh[jt], acc[mt][jt]);
            }
    }

#pragma unroll
    for (int mt = 0; mt < 4; mt++)
#pragma unroll
        for (int jt = 0; jt < 2; jt++)
#pragma unroll
            for (int r = 0; r < 4; r++)
                Sp[w][(mt * 16 + q * 4 + r) * 32 + jt * 16 + lc] = acc[mt][jt][r];
    __syncthreads();

    float pa = prelu_a[0];
#pragma unroll
    for (int gi = 0; gi < 2; gi++) {
        int g = tid + gi * 256;
        int j = g & 31, mg = g >> 5;
        int m = mg * 4;
        int jj = j0 + j;
        if (jj >= 961) continue;
        float v[4];
#pragma unroll
        for (int i = 0; i < 4; i++) {
            int idx = (m + i) * 32 + j;
            v[i] = Sp[0][idx] + Sp[1][idx] + Sp[2][idx] + Sp[3][idx];
            v[i] = v[i] * sc[m + i] + sh[m + i];
            v[i] = v[i] >= 0.f ? v[i] : pa * v[i];
        }
        ushort_t a0, b0, a1, b1, a2, b2, a3, b3;
        split2(v[0], a0, b0); split2(v[1], a1, b1);
        split2(v[2], a2, b2); split2(v[3], a3, b3);
        *(ushort4*)(ebh + (size_t)jj * 64 + m) = make_ushort4(a0, a1, a2, a3);
        *(ushort4*)(ebl + (size_t)jj * 64 + m) = make_ushort4(b0, b1, b2, b3);
    }
}

// ---------------------------------------------------------------------
// HSPA: S = e^T e -> sparsemax (Michelot) -> P^T bf16. grid (B, 61).
// ---------------------------------------------------------------------
__global__ __launch_bounds__(512) void hspa_mfma_kernel(
    const ushort_t* __restrict__ eh, const ushort_t* __restrict__ el,
    ushort_t* __restrict__ PT)
{
    const int PITCH = 978;
    __shared__ float S[16 * 978];
    int b = blockIdx.x, nb = blockIdx.y;
    const ushort_t* ebh = eh + (size_t)b * 1024 * 64;
    const ushort_t* ebl = el + (size_t)b * 1024 * 64;
    ushort_t* Pb = PT + (size_t)b * 1024 * 992;
    int tid = threadIdx.x, w = tid >> 6, l = tid & 63, lc = l & 15, q = l >> 4;
    int n0 = nb * 16;

    short8 a0h = *(const short8*)(ebh + (size_t)(n0 + lc) * 64 + q * 8);
    short8 a0l = *(const short8*)(ebl + (size_t)(n0 + lc) * 64 + q * 8);
    short8 a1h = *(const short8*)(ebh + (size_t)(n0 + lc) * 64 + 32 + q * 8);
    short8 a1l = *(const short8*)(ebl + (size_t)(n0 + lc) * 64 + 32 + q * 8);

    for (int jt = w; jt < 61; jt += 8) {
        int j = jt * 16 + lc;
        short8 b0h = *(const short8*)(ebh + (size_t)j * 64 + q * 8);
        short8 b0l = *(const short8*)(ebl + (size_t)j * 64 + q * 8);
        short8 b1h = *(const short8*)(ebh + (size_t)j * 64 + 32 + q * 8);
        short8 b1l = *(const short8*)(ebl + (size_t)j * 64 + 32 + q * 8);
        floatx4 acc = (floatx4){0.f, 0.f, 0.f, 0.f};
        acc = MFMA(a0h, b0h, acc);
        acc = MFMA(a0h, b0l, acc);
        acc = MFMA(a0l, b0h, acc);
        acc = MFMA(a1h, b1h, acc);
        acc = MFMA(a1h, b1l, acc);
        acc = MFMA(a1l, b1h, acc);
#pragma unroll
        for (int r = 0; r < 4; r++) S[(q * 4 + r) * PITCH + j] = acc[r];
    }
    __syncthreads();

    int r0 = w * 2, r1 = w * 2 + 1;
    float sv0[16], sv1[16];
    float mx0 = -INFINITY, mx1 = -INFINITY;
#pragma unroll
    for (int t = 0; t < 16; t++) {
        int j = l + t * 64;
        float s0 = (j < 961) ? S[r0 * PITCH + j] : -INFINITY;
        float s1 = (j < 961) ? S[r1 * PITCH + j] : -INFINITY;
        sv0[t] = s0; sv1[t] = s1;
        mx0 = fmaxf(mx0, s0); mx1 = fmaxf(mx1, s1);
    }
    for (int off = 32; off; off >>= 1) {
        mx0 = fmaxf(mx0, __shfl_xor(mx0, off));
        mx1 = fmaxf(mx1, __shfl_xor(mx1, off));
    }
#pragma unroll
    for (int t = 0; t < 16; t++) { sv0[t] -= mx0; sv1[t] -= mx1; }

    float tau0 = -1.f, tau1 = -1.f;
    for (int it = 0; it < 16; it++) {
        float s0 = 0.f, c0 = 0.f, s1 = 0.f, c1 = 0.f;
#pragma unroll
        for (int t = 0; t < 16; t++) {
            if (sv0[t] > tau0) { s0 += sv0[t]; c0 += 1.f; }
            if (sv1[t] > tau1) { s1 += sv1[t]; c1 += 1.f; }
        }
        for (int off = 32; off; off >>= 1) {
            s0 += __shfl_xor(s0, off); c0 += __shfl_xor(c0, off);
            s1 += __shfl_xor(s1, off); c1 += __shfl_xor(c1, off);
        }
        float nt0 = (s0 - 1.f) / c0;
        float nt1 = (s1 - 1.f) / c1;
        bool conv = (nt0 == tau0) && (nt1 == tau1);
        tau0 = nt0; tau1 = nt1;
        if (conv) break;
    }
#pragma unroll
    for (int t = 0; t < 16; t++) {
        int j = l + t * 64;
        if (j < 976) {
            S[r0 * PITCH + j] = (j < 961) ? fmaxf(sv0[t] - tau0, 0.f) : 0.f;
            S[r1 * PITCH + j] = (j < 961) ? fmaxf(sv1[t] - tau1, 0.f) : 0.f;
        }
    }
    __syncthreads();

    for (int j = tid; j < 976; j += 512) {
        union { ushort_t u[8]; uint4 v; } p0, p1;
#pragma unroll
        for (int r = 0; r < 8; r++)  p0.u[r] = f2bf(S[r * PITCH + j]);
#pragma unroll
        for (int r = 0; r < 8; r++)  p1.u[r] = f2bf(S[(8 + r) * PITCH + j]);
        ushort_t* dst = Pb + (size_t)j * 992 + n0;
        *(uint4*)(dst) = p0.v;
        *(uint4*)(dst + 8) = p1.v;
    }
}

// ---------------------------------------------------------------------
// out = gat @ P + gat. grid (B, 16) batch-major.
// ---------------------------------------------------------------------
__global__ __launch_bounds__(256) void out_mfma_kernel(
    const ushort_t* __restrict__ gat_nf, const ushort_t* __restrict__ PT,
    float* __restrict__ out)
{
    int b = blockIdx.x, jb = blockIdx.y;
    const ushort_t* gb = gat_nf + (size_t)b * 256 * 992;
    const ushort_t* Pb = PT + (size_t)b * 1024 * 992;
    float* ob = out + (size_t)b * 256 * 961;
    int tid = threadIdx.x, w = tid >> 6, l = tid & 63, lc = l & 15, q = l >> 4;
    int m0 = w * 64, j0 = jb * 64;

    floatx4 acc[4][4];
#pragma unroll
    for (int i = 0; i < 4; i++)
#pragma unroll
        for (int j = 0; j < 4; j++) acc[i][j] = (floatx4){0.f, 0.f, 0.f, 0.f};

    for (int k0 = 0; k0 < 992; k0 += 32) {
        short8 a[4], bb[4];
#pragma unroll
        for (int mt = 0; mt < 4; mt++)
            a[mt] = *(const short8*)(gb + (size_t)(m0 + mt * 16 + lc) * 992 + k0 + q * 8);
#pragma unroll
        for (int jt = 0; jt < 4; jt++)
            bb[jt] = *(const short8*)(Pb + (size_t)(j0 + jt * 16 + lc) * 992 + k0 + q * 8);
#pragma unroll
        for (int mt = 0; mt < 4; mt++)
#pragma unroll
            for (int jt = 0; jt < 4; jt++)
                acc[mt][jt] = MFMA(a[mt], bb[jt], acc[mt][jt]);
    }
#pragma unroll
    for (int mt = 0; mt < 4; mt++) {
        int mb = m0 + mt * 16 + q * 4;
#pragma unroll
        for (int jt = 0; jt < 4; jt++) {
            int j = j0 + jt * 16 + lc;
            if (j >= 961) continue;
#pragma unroll
            for (int r = 0; r < 4; r++) {
                float g = bf2f(gb[(size_t)(mb + r) * 992 + j]);
                ob[(size_t)(mb + r) * 961 + j] = acc[mt][jt][r] + g;
            }
        }
    }
}

// =====================================================================
extern "C" void kernel_launch(void* const* d_in, const int* in_sizes, int n_in,
                              void* d_out, int out_size, void* d_ws, size_t ws_size,
                              hipStream_t stream)
{
    const float* zf      = (const float*)d_in[0];
    const float* xf      = (const float*)d_in[1];
    const float* Wq      = (const float*)d_in[2];
    const float* bq      = (const float*)d_in[3];
    const float* Ws      = (const float*)d_in[4];
    const float* bs      = (const float*)d_in[5];
    const float* Wg      = (const float*)d_in[6];
    const float* bg      = (const float*)d_in[7];
    const float* g_gamma = (const float*)d_in[8];
    const float* g_beta  = (const float*)d_in[9];
    const float* g_mean  = (const float*)d_in[10];
    const float* g_var   = (const float*)d_in[11];
    const float* Wfi     = (const float*)d_in[12];
    const float* bfi     = (const float*)d_in[13];
    const float* fi_gamma= (const float*)d_in[14];
    const float* fi_beta = (const float*)d_in[15];
    const float* fi_mean = (const float*)d_in[16];
    const float* fi_var  = (const float*)d_in[17];
    const float* Wm      = (const float*)d_in[18];
    const float* bm      = (const float*)d_in[19];
    const float* m_gamma = (const float*)d_in[20];
    const float* m_beta  = (const float*)d_in[21];
    const float* m_mean  = (const float*)d_in[22];
    const float* m_var   = (const float*)d_in[23];
    const float* prelu_a = (const float*)d_in[24];
    float* out = (float*)d_out;

    ushort_t* ws = (ushort_t*)d_ws;
    ushort_t* Wq_h  = ws + 0;         ushort_t* Wq_l  = ws + 65536;
    ushort_t* Ws_h  = ws + 131072;    ushort_t* Ws_l  = ws + 196608;
    ushort_t* Wg_h  = ws + 262144;    ushort_t* Wg_l  = ws + 327680;
    ushort_t* Wfi_h = ws + 393216;    ushort_t* Wfi_l = ws + 524288;
    ushort_t* wm_h  = ws + 655360;    ushort_t* wm_l  = ws + 802816;
    ushort_t* XT_h    = ws + 950272;      // 8,126,464 each
    ushort_t* XT_l    = ws + 9076736;
    ushort_t* xf_tT_h = ws + 17203200;
    ushort_t* xf_tT_l = ws + 25329664;
    ushort_t* zf_tT_h = ws + 33456128;    // 524,288 each
    ushort_t* zf_tT_l = ws + 33980416;
    ushort_t* zf_gT_h = ws + 34504704;
    ushort_t* zf_gT_l = ws + 35028992;
    ushort_t* gxT_h   = ws + 17203200;    // aliases xf_tT region (dead after attn)
    ushort_t* gxT_l   = ws + 26124288;
    ushort_t* xf_gT_h = ws + 35553280;
    ushort_t* xf_gT_l = ws + 43679744;
    ushort_t* gat_nf  = ws + 51806208;    // 8,126,464
    ushort_t* eT_h    = ws + 59932672;    // 2,097,152 each
    ushort_t* eT_l    = ws + 62029824;
    ushort_t* PT      = ws + 64126976;    // 32,505,856
    ushort_t* zfT_h   = ws + 96632832;    // 524,288 each
    ushort_t* zfT_l   = ws + 97157120;
    float* scsh       = (float*)(ws + 97681408);   // 2176 floats
    ushort_t* zgC_h   = ws + 97685760;    // 524,288 each
    ushort_t* zgC_l   = ws + 98210048;
    ushort_t* embT_h = XT_h;
    ushort_t* embT_l = XT_l;

    const float* sc_q  = scsh + 0,    *sh_q  = scsh + 256;
    const float* sc_s  = scsh + 512,  *sh_s  = scsh + 768;
    const float* sc_g  = scsh + 1024, *sh_g  = scsh + 1280;
    const float* sc_fi = scsh + 1536, *sh_fi = scsh + 1792;
    const float* sc_m  = scsh + 2048, *sh_m  = scsh + 2112;

    prep_all_kernel<<<1857, 256, 0, stream>>>(
        Wq, Ws, Wg, Wfi, Wm,
        bq, bs, bg, g_gamma, g_beta, g_mean, g_var,
        bfi, fi_gamma, fi_beta, fi_mean, fi_var,
        bm, m_gamma, m_beta, m_mean, m_var,
        Wq_h, Wq_l, Ws_h, Ws_l, Wg_h, Wg_l, Wfi_h, Wfi_l, wm_h, wm_l, scsh);

    transpose_in_kernel<<<dim3(31, 8, 32), 256, 0, stream>>>(xf, XT_h, XT_l, 961, 992);
    transpose_in_kernel<<<dim3(2, 8, 32), 256, 0, stream>>>(zf, zfT_h, zfT_l, 49, 64);

    // batch-major grids: all tiles of batch b land on XCD b%8 (L2 locality)
    dualconv_mfma_kernel<<<dim3(32, 31), 512, 0, stream>>>(
        XT_h, XT_l, Wq_h, Wq_l, Wg_h, Wg_l,
        sc_q, sh_q, sc_g, sh_g, 0, 1,
        xf_tT_h, xf_tT_l, xf_gT_h, xf_gT_l,
        nullptr, nullptr, 0, 256, 961, 992, 992);
    dualconv_mfma_kernel<<<dim3(32, 2), 512, 0, stream>>>(
        zfT_h, zfT_l, Ws_h, Ws_l, Wg_h, Wg_l,
        sc_s, sh_s, sc_g, sh_g, 0, 1,
        zf_tT_h, zf_tT_l, zf_gT_h, zf_gT_l,
        zgC_h, zgC_l, 64, 256, 49, 64, 64);

    attn_mfma_kernel<<<dim3(32, 16), 256, 0, stream>>>(
        xf_tT_h, xf_tT_l, zf_tT_h, zf_tT_l, zgC_h, zgC_l, embT_h, embT_l);

    halo_zero_kernel<<<16, 256, 0, stream>>>(gxT_h, gxT_l);

    fi_mfma_kernel<<<dim3(32, 31), 256, 0, stream>>>(
        embT_h, embT_l, xf_gT_h, xf_gT_l, Wfi_h, Wfi_l, sc_fi, sh_fi,
        gxT_h, gxT_l, gat_nf);

    conv3x3_mfma_kernel<<<dim3(32, 31), 256, 0, stream>>>(
        gxT_h, gxT_l, wm_h, wm_l, sc_m, sh_m, prelu_a, eT_h, eT_l);

    hspa_mfma_kernel<<<dim3(32, 61), 512, 0, stream>>>(eT_h, eT_l, PT);

    out_mfma_kernel<<<dim3(32, 16), 256, 0, stream>>>(gat_nf, PT, out);
}

// Round 11
// 645.168 us; speedup vs baseline: 1.1846x; 1.0259x over previous
//
#include <hip/hip_runtime.h>
#include <cstdint>
#include <cstddef>
#include <math.h>

typedef __attribute__((ext_vector_type(8))) short short8;
typedef __attribute__((ext_vector_type(4))) float floatx4;
typedef unsigned short ushort_t;

__device__ __forceinline__ ushort_t f2bf(float x) {
    union { float f; unsigned u; } v; v.f = x;
    unsigned r = v.u + 0x7FFF + ((v.u >> 16) & 1);
    return (ushort_t)(r >> 16);
}
__device__ __forceinline__ float bf2f(ushort_t h) {
    union { unsigned u; float f; } v; v.u = ((unsigned)h) << 16; return v.f;
}
__device__ __forceinline__ void split2(float v, ushort_t& h, ushort_t& l) {
    h = f2bf(v);
    l = f2bf(v - bf2f(h));
}

#define MFMA(a, b, c) __builtin_amdgcn_mfma_f32_16x16x32_bf16((a), (b), (c), 0, 0, 0)

// ---------------------------------------------------------------------
// prep_all: all weight hi/lo splits + Wm transpose + BN fold, one launch.
// ---------------------------------------------------------------------
__global__ void prep_all_kernel(
    const float* __restrict__ Wq, const float* __restrict__ Ws,
    const float* __restrict__ Wg, const float* __restrict__ Wfi,
    const float* __restrict__ Wm,
    const float* bq, const float* bs,
    const float* bg, const float* gg, const float* gb, const float* gm, const float* gv,
    const float* bfi, const float* fg, const float* fb, const float* fm, const float* fv,
    const float* bm, const float* mg, const float* mb, const float* mm, const float* mv,
    ushort_t* Wq_h, ushort_t* Wq_l, ushort_t* Ws_h, ushort_t* Ws_l,
    ushort_t* Wg_h, ushort_t* Wg_l, ushort_t* Wfi_h, ushort_t* Wfi_l,
    ushort_t* wm_h, ushort_t* wm_l, float* scsh)
{
    int bid = blockIdx.x, t = threadIdx.x;
    if (bid < 256) {
        int i = bid * 256 + t; ushort_t h, l; split2(Wq[i], h, l); Wq_h[i] = h; Wq_l[i] = l;
    } else if (bid < 512) {
        int i = (bid - 256) * 256 + t; ushort_t h, l; split2(Ws[i], h, l); Ws_h[i] = h; Ws_l[i] = l;
    } else if (bid < 768) {
        int i = (bid - 512) * 256 + t; ushort_t h, l; split2(Wg[i], h, l); Wg_h[i] = h; Wg_l[i] = l;
    } else if (bid < 1280) {
        int i = (bid - 768) * 256 + t; ushort_t h, l; split2(Wfi[i], h, l); Wfi_h[i] = h; Wfi_l[i] = l;
    } else if (bid < 1856) {
        int i = (bid - 1280) * 256 + t;  // [tap][m][c] flattened
        int c = i & 255, m = (i >> 8) & 63, tap = i >> 14;
        ushort_t h, l; split2(Wm[((size_t)m * 256 + c) * 9 + tap], h, l);
        wm_h[i] = h; wm_l[i] = l;
    } else {
        if (t < 256) {
            scsh[t] = 1.f;        scsh[256 + t] = bq[t];
            scsh[512 + t] = 1.f;  scsh[768 + t] = bs[t];
            float s = gg[t] * rsqrtf(gv[t] + 1e-5f);
            scsh[1024 + t] = s;   scsh[1280 + t] = gb[t] + s * (bg[t] - gm[t]);
            float s2 = fg[t] * rsqrtf(fv[t] + 1e-5f);
            scsh[1536 + t] = s2;  scsh[1792 + t] = fb[t] + s2 * (bfi[t] - fm[t]);
            if (t < 64) {
                float s3 = mg[t] * rsqrtf(mv[t] + 1e-5f);
                scsh[2048 + t] = s3; scsh[2112 + t] = mb[t] + s3 * (bm[t] - mm[t]);
            }
        }
    }
}

// halo-only zero of gxT (128 halo rows per batch, hi+lo)
__global__ void halo_zero_kernel(ushort_t* __restrict__ gxh, ushort_t* __restrict__ gxl) {
    int i = blockIdx.x * 256 + threadIdx.x;   // 0..4095
    int b = i >> 7, k = i & 127;
    int r;
    if (k < 33) r = k;
    else if (k < 66) r = 32 * 33 + (k - 33);
    else { int k2 = k - 66; r = ((k2 >> 1) + 1) * 33 + ((k2 & 1) ? 32 : 0); }
    uint4* ph = (uint4*)(gxh + ((size_t)b * 1089 + r) * 256);
    uint4* pl = (uint4*)(gxl + ((size_t)b * 1089 + r) * 256);
    uint4 z = make_uint4(0, 0, 0, 0);
#pragma unroll
    for (int s = 0; s < 32; s++) { ph[s] = z; pl[s] = z; }
}

// fp32 [B][256][Nsrc] -> bf16 hi/lo [B][Npad][256]
__global__ __launch_bounds__(256) void transpose_in_kernel(
    const float* __restrict__ in, ushort_t* __restrict__ oh, ushort_t* __restrict__ ol,
    int Nsrc, int Npad)
{
    int b = blockIdx.z;
    const float* ib = in + (size_t)b * 256 * Nsrc;
    ushort_t* obh = oh + (size_t)b * Npad * 256;
    ushort_t* obl = ol + (size_t)b * Npad * 256;
    __shared__ float tile[32][33];
    int n0 = blockIdx.x * 32, c0 = blockIdx.y * 32;
    int tx = threadIdx.x & 31, ty = threadIdx.x >> 5;
#pragma unroll
    for (int r = 0; r < 4; r++) {
        int c = c0 + ty + r * 8, n = n0 + tx;
        tile[ty + r * 8][tx] = (n < Nsrc) ? ib[(size_t)c * Nsrc + n] : 0.f;
    }
    __syncthreads();
#pragma unroll
    for (int r = 0; r < 4; r++) {
        int n = n0 + ty + r * 8, c = c0 + tx;
        if (n < Nsrc) {
            ushort_t h, l; split2(tile[tx][ty + r * 8], h, l);
            obh[(size_t)n * 256 + c] = h;
            obl[(size_t)n * 256 + c] = l;
        }
    }
}

// ---------------------------------------------------------------------
// dual conv1x1, WIDE tile: wave = 64m x 64n (acc[4][4], 48 MFMA / 16 loads).
// 256 threads = 4 waves covering 256 m. blockIdx.y = (ntile<<1)|half.
// grid (B, 2*ntiles) — batch-major for XCD L2 locality.
// ---------------------------------------------------------------------
__global__ __launch_bounds__(256) void dualconv_mfma_kernel(
    const ushort_t* __restrict__ Xh, const ushort_t* __restrict__ Xl,
    const ushort_t* __restrict__ W1h, const ushort_t* __restrict__ W1l,
    const ushort_t* __restrict__ W2h, const ushort_t* __restrict__ W2l,
    const float* __restrict__ sc1, const float* __restrict__ sh1,
    const float* __restrict__ sc2, const float* __restrict__ sh2,
    int relu1, int relu2,
    ushort_t* __restrict__ O1h, ushort_t* __restrict__ O1l,
    ushort_t* __restrict__ O2h, ushort_t* __restrict__ O2l,
    ushort_t* __restrict__ O2ch, ushort_t* __restrict__ O2cl, int cpitch,
    int K, int Nvalid, int NpadIn, int NpadOut)
{
    int b = blockIdx.x;
    int half = blockIdx.y & 1;
    int n0 = (blockIdx.y >> 1) * 64;
    const ushort_t* Xbh = Xh + (size_t)b * NpadIn * K;
    const ushort_t* Xbl = Xl + (size_t)b * NpadIn * K;
    int tid = threadIdx.x, w = tid >> 6, l = tid & 63, lc = l & 15, q = l >> 4;
    int m0 = w * 64;

    const ushort_t* Wh = half ? W2h : W1h;
    const ushort_t* Wl = half ? W2l : W1l;
    const float* sc = half ? sc2 : sc1;
    const float* sh = half ? sh2 : sh1;
    int relu = half ? relu2 : relu1;
    ushort_t* Obh = (half ? O2h : O1h) + (size_t)b * NpadOut * 256;
    ushort_t* Obl = (half ? O2l : O1l) + (size_t)b * NpadOut * 256;

    // clamped load rows for the tail tile (results discarded by n guard)
    int nrow[4];
#pragma unroll
    for (int jt = 0; jt < 4; jt++) {
        int nr = n0 + jt * 16 + lc;
        nrow[jt] = (nr < NpadIn) ? nr : (NpadIn - 1);
    }

    floatx4 acc[4][4];
#pragma unroll
    for (int i = 0; i < 4; i++)
#pragma unroll
        for (int j = 0; j < 4; j++) acc[i][j] = (floatx4){0.f, 0.f, 0.f, 0.f};

    for (int k0 = 0; k0 < K; k0 += 32) {
        short8 ah[4], al[4], bh[4], bl[4];
#pragma unroll
        for (int mt = 0; mt < 4; mt++) {
            size_t off = (size_t)(m0 + mt * 16 + lc) * K + k0 + q * 8;
            ah[mt] = *(const short8*)(Wh + off);
            al[mt] = *(const short8*)(Wl + off);
        }
#pragma unroll
        for (int jt = 0; jt < 4; jt++) {
            size_t off = (size_t)nrow[jt] * K + k0 + q * 8;
            bh[jt] = *(const short8*)(Xbh + off);
            bl[jt] = *(const short8*)(Xbl + off);
        }
#pragma unroll
        for (int mt = 0; mt < 4; mt++)
#pragma unroll
            for (int jt = 0; jt < 4; jt++) {
                acc[mt][jt] = MFMA(ah[mt], bh[jt], acc[mt][jt]);
                acc[mt][jt] = MFMA(ah[mt], bl[jt], acc[mt][jt]);
                acc[mt][jt] = MFMA(al[mt], bh[jt], acc[mt][jt]);
            }
    }
#pragma unroll
    for (int mt = 0; mt < 4; mt++) {
        int mb = m0 + mt * 16 + q * 4;
        float s0 = sc[mb], s1 = sc[mb + 1], s2 = sc[mb + 2], s3 = sc[mb + 3];
        float h0 = sh[mb], h1 = sh[mb + 1], h2 = sh[mb + 2], h3 = sh[mb + 3];
#pragma unroll
        for (int jt = 0; jt < 4; jt++) {
            int n = n0 + jt * 16 + lc;
            if (n >= Nvalid) continue;
            float v0 = acc[mt][jt][0] * s0 + h0;
            float v1 = acc[mt][jt][1] * s1 + h1;
            float v2 = acc[mt][jt][2] * s2 + h2;
            float v3 = acc[mt][jt][3] * s3 + h3;
            if (relu) { v0 = fmaxf(v0, 0.f); v1 = fmaxf(v1, 0.f); v2 = fmaxf(v2, 0.f); v3 = fmaxf(v3, 0.f); }
            ushort_t e0, f0, e1, f1, e2, f2, e3, f3;
            split2(v0, e0, f0); split2(v1, e1, f1); split2(v2, e2, f2); split2(v3, e3, f3);
            *(ushort4*)(Obh + (size_t)n * 256 + mb) = make_ushort4(e0, e1, e2, e3);
            *(ushort4*)(Obl + (size_t)n * 256 + mb) = make_ushort4(f0, f1, f2, f3);
            if (half && O2ch) {
                O2ch[((size_t)b * 256 + mb + 0) * cpitch + n] = e0;
                O2ch[((size_t)b * 256 + mb + 1) * cpitch + n] = e1;
                O2ch[((size_t)b * 256 + mb + 2) * cpitch + n] = e2;
                O2ch[((size_t)b * 256 + mb + 3) * cpitch + n] = e3;
                O2cl[((size_t)b * 256 + mb + 0) * cpitch + n] = f0;
                O2cl[((size_t)b * 256 + mb + 1) * cpitch + n] = f1;
                O2cl[((size_t)b * 256 + mb + 2) * cpitch + n] = f2;
                O2cl[((size_t)b * 256 + mb + 3) * cpitch + n] = f3;
            }
        }
    }
}

// ---------------------------------------------------------------------
// attention via MFMA: sim GEMM -> fp32 softmax -> emb GEMM. grid (B, 16).
// ---------------------------------------------------------------------
__global__ __launch_bounds__(256) void attn_mfma_kernel(
    const ushort_t* __restrict__ xth, const ushort_t* __restrict__ xtl,
    const ushort_t* __restrict__ zth, const ushort_t* __restrict__ ztl,
    const ushort_t* __restrict__ zgh, const ushort_t* __restrict__ zgl,
    ushort_t* __restrict__ eh, ushort_t* __restrict__ el)
{
    __shared__ float S[64][68];
    __shared__ ushort_t awh[64][72], awl[64][72];
    __shared__ float T[4][16][20];
    int b = blockIdx.x, n0 = blockIdx.y * 64;
    int tid = threadIdx.x, w = tid >> 6, l = tid & 63, lc = l & 15, q = l >> 4;
    const ushort_t* xhb = xth + (size_t)b * 992 * 256;
    const ushort_t* xlb = xtl + (size_t)b * 992 * 256;
    const ushort_t* zhb = zth + (size_t)b * 64 * 256;
    const ushort_t* zlb = ztl + (size_t)b * 64 * 256;
    const ushort_t* ghb = zgh + (size_t)b * 256 * 64;
    const ushort_t* glb = zgl + (size_t)b * 256 * 64;

    int rowg = n0 + w * 16 + lc;
#pragma unroll
    for (int ct = 0; ct < 4; ct++) {
        floatx4 acc = (floatx4){0.f, 0.f, 0.f, 0.f};
        for (int k0 = 0; k0 < 256; k0 += 32) {
            short8 ah = *(const short8*)(xhb + (size_t)rowg * 256 + k0 + q * 8);
            short8 al = *(const short8*)(xlb + (size_t)rowg * 256 + k0 + q * 8);
            short8 bh = *(const short8*)(zhb + (size_t)(ct * 16 + lc) * 256 + k0 + q * 8);
            short8 bl = *(const short8*)(zlb + (size_t)(ct * 16 + lc) * 256 + k0 + q * 8);
            acc = MFMA(ah, bh, acc);
            acc = MFMA(ah, bl, acc);
            acc = MFMA(al, bh, acc);
        }
#pragma unroll
        for (int r = 0; r < 4; r++) S[w * 16 + q * 4 + r][ct * 16 + lc] = acc[r];
    }
    __syncthreads();
    if (tid < 64) {
        float mx = -INFINITY;
        for (int m = 0; m < 49; m++) mx = fmaxf(mx, S[tid][m]);
        float sum = 0.f;
        for (int m = 0; m < 49; m++) { float e = __expf(S[tid][m] - mx); S[tid][m] = e; sum += e; }
        float inv = 1.f / sum;
        for (int m = 0; m < 64; m++) {
            float vv = (m < 49) ? S[tid][m] * inv : 0.f;
            ushort_t hh, ll; split2(vv, hh, ll);
            awh[tid][m] = hh; awl[tid][m] = ll;
        }
    }
    __syncthreads();
    int nw = l >> 2, cg = l & 3;
#pragma unroll
    for (int ct = 0; ct < 16; ct++) {
        floatx4 acc = (floatx4){0.f, 0.f, 0.f, 0.f};
#pragma unroll
        for (int k0 = 0; k0 < 64; k0 += 32) {
            short8 ah = *(const short8*)(&awh[w * 16 + lc][k0 + q * 8]);
            short8 al = *(const short8*)(&awl[w * 16 + lc][k0 + q * 8]);
            short8 bh = *(const short8*)(ghb + (size_t)(ct * 16 + lc) * 64 + k0 + q * 8);
            short8 bl = *(const short8*)(glb + (size_t)(ct * 16 + lc) * 64 + k0 + q * 8);
            acc = MFMA(ah, bh, acc);
            acc = MFMA(ah, bl, acc);
            acc = MFMA(al, bh, acc);
        }
#pragma unroll
        for (int r = 0; r < 4; r++) T[w][q * 4 + r][lc] = acc[r];
        float4 vv = *(const float4*)&T[w][nw][cg * 4];
        int n = n0 + w * 16 + nw;
        if (n < 961) {
            ushort_t h0, l0, h1, l1, h2, l2_, h3, l3;
            split2(vv.x, h0, l0); split2(vv.y, h1, l1);
            split2(vv.z, h2, l2_); split2(vv.w, h3, l3);
            size_t off = ((size_t)b * 992 + n) * 256 + ct * 16 + cg * 4;
            *(ushort4*)(eh + off) = make_ushort4(h0, h1, h2, h3);
            *(ushort4*)(el + off) = make_ushort4(l0, l1, l2_, l3);
        }
    }
}

// ---------------------------------------------------------------------
// fi conv (K=512 concat(emb, xf_g), hi/lo). grid (B, 31).
// ---------------------------------------------------------------------
__global__ __launch_bounds__(256) void fi_mfma_kernel(
    const ushort_t* __restrict__ Eh, const ushort_t* __restrict__ El,
    const ushort_t* __restrict__ Gh, const ushort_t* __restrict__ Gl,
    const ushort_t* __restrict__ Wh, const ushort_t* __restrict__ Wl,
    const float* __restrict__ sc, const float* __restrict__ sh,
    ushort_t* __restrict__ gxh, ushort_t* __restrict__ gxl,
    ushort_t* __restrict__ gat_nf)
{
    int b = blockIdx.x;
    const ushort_t* Ebh = Eh + (size_t)b * 992 * 256;
    const ushort_t* Ebl = El + (size_t)b * 992 * 256;
    const ushort_t* Gbh = Gh + (size_t)b * 992 * 256;
    const ushort_t* Gbl = Gl + (size_t)b * 992 * 256;
    ushort_t* gxhb = gxh + (size_t)b * 1089 * 256;
    ushort_t* gxlb = gxl + (size_t)b * 1089 * 256;
    ushort_t* gn = gat_nf + (size_t)b * 256 * 992;
    int tid = threadIdx.x, w = tid >> 6, l = tid & 63, lc = l & 15, q = l >> 4;
    int m0 = w * 64, nb0 = blockIdx.y * 32;

    floatx4 acc[4][2];
#pragma unroll
    for (int i = 0; i < 4; i++)
#pragma unroll
        for (int j = 0; j < 2; j++) acc[i][j] = (floatx4){0.f, 0.f, 0.f, 0.f};

    for (int k0 = 0; k0 < 512; k0 += 32) {
        const ushort_t* sh_ = (k0 < 256) ? Ebh : Gbh;
        const ushort_t* sl_ = (k0 < 256) ? Ebl : Gbl;
        int kk = (k0 < 256) ? k0 : k0 - 256;
        short8 ah[4], al[4], bh[2], bl[2];
#pragma unroll
        for (int mt = 0; mt < 4; mt++) {
            size_t off = (size_t)(m0 + mt * 16 + lc) * 512 + k0 + q * 8;
            ah[mt] = *(const short8*)(Wh + off);
            al[mt] = *(const short8*)(Wl + off);
        }
#pragma unroll
        for (int jt = 0; jt < 2; jt++) {
            size_t off = (size_t)(nb0 + jt * 16 + lc) * 256 + kk + q * 8;
            bh[jt] = *(const short8*)(sh_ + off);
            bl[jt] = *(const short8*)(sl_ + off);
        }
#pragma unroll
        for (int mt = 0; mt < 4; mt++)
#pragma unroll
            for (int jt = 0; jt < 2; jt++) {
                acc[mt][jt] = MFMA(ah[mt], bh[jt], acc[mt][jt]);
                acc[mt][jt] = MFMA(ah[mt], bl[jt], acc[mt][jt]);
                acc[mt][jt] = MFMA(al[mt], bh[jt], acc[mt][jt]);
            }
    }
#pragma unroll
    for (int mt = 0; mt < 4; mt++) {
        int mb = m0 + mt * 16 + q * 4;
        float s0 = sc[mb], s1 = sc[mb + 1], s2 = sc[mb + 2], s3 = sc[mb + 3];
        float h0 = sh[mb], h1 = sh[mb + 1], h2 = sh[mb + 2], h3 = sh[mb + 3];
#pragma unroll
        for (int jt = 0; jt < 2; jt++) {
            int n = nb0 + jt * 16 + lc;
            if (n >= 961) continue;
            float v0 = fmaxf(acc[mt][jt][0] * s0 + h0, 0.f);
            float v1 = fmaxf(acc[mt][jt][1] * s1 + h1, 0.f);
            float v2 = fmaxf(acc[mt][jt][2] * s2 + h2, 0.f);
            float v3 = fmaxf(acc[mt][jt][3] * s3 + h3, 0.f);
            ushort_t a0, b0, a1, b1, a2, b2, a3, b3;
            split2(v0, a0, b0); split2(v1, a1, b1); split2(v2, a2, b2); split2(v3, a3, b3);
            int hh = n / 31, ww2 = n - hh * 31;
            int row = (hh + 1) * 33 + (ww2 + 1);
            *(ushort4*)(gxhb + (size_t)row * 256 + mb) = make_ushort4(a0, a1, a2, a3);
            *(ushort4*)(gxlb + (size_t)row * 256 + mb) = make_ushort4(b0, b1, b2, b3);
            gn[(size_t)(mb + 0) * 992 + n] = a0;
            gn[(size_t)(mb + 1) * 992 + n] = a1;
            gn[(size_t)(mb + 2) * 992 + n] = a2;
            gn[(size_t)(mb + 3) * 992 + n] = a3;
        }
    }
}

// ---------------------------------------------------------------------
// conv3x3 split-K: block = 4 waves over ONE 64m x 32j tile, 72 (tap,k0)
// steps split 18/wave, partials reduced in LDS. grid (B, 31) batch-major.
// ---------------------------------------------------------------------
__global__ __launch_bounds__(256) void conv3x3_mfma_kernel(
    const ushort_t* __restrict__ gxh, const ushort_t* __restrict__ gxl,
    const ushort_t* __restrict__ wmh, const ushort_t* __restrict__ wml,
    const float* __restrict__ sc, const float* __restrict__ sh,
    const float* __restrict__ prelu_a,
    ushort_t* __restrict__ eh, ushort_t* __restrict__ el)
{
    __shared__ float Sp[4][2048];   // 4 waves x (64m x 32j) partials, 32 KB
    int b = blockIdx.x;
    const ushort_t* gxhb = gxh + (size_t)b * 1089 * 256;
    const ushort_t* gxlb = gxl + (size_t)b * 1089 * 256;
    ushort_t* ebh = eh + (size_t)b * 1024 * 64;
    ushort_t* ebl = el + (size_t)b * 1024 * 64;
    int tid = threadIdx.x, w = tid >> 6, l = tid & 63, lc = l & 15, q = l >> 4;
    int j0 = blockIdx.y * 32;

    int base[2];
#pragma unroll
    for (int jt = 0; jt < 2; jt++) {
        int j = j0 + jt * 16 + lc; if (j > 960) j = 960;
        int hh = j / 31, ww2 = j - hh * 31;
        base[jt] = (hh + 1) * 33 + (ww2 + 1);
    }

    floatx4 acc[4][2];
#pragma unroll
    for (int i = 0; i < 4; i++)
#pragma unroll
        for (int j = 0; j < 2; j++) acc[i][j] = (floatx4){0.f, 0.f, 0.f, 0.f};

    for (int s = w * 18; s < w * 18 + 18; s++) {
        int tap = s >> 3, k0 = (s & 7) * 32;
        int doff = (tap / 3 - 1) * 33 + (tap % 3 - 1);
        const ushort_t* wth = wmh + tap * 16384;
        const ushort_t* wtl = wml + tap * 16384;
        short8 ah[4], al_[4], bh[2], bl[2];
#pragma unroll
        for (int mt = 0; mt < 4; mt++) {
            size_t off = (size_t)(mt * 16 + lc) * 256 + k0 + q * 8;
            ah[mt]  = *(const short8*)(wth + off);
            al_[mt] = *(const short8*)(wtl + off);
        }
#pragma unroll
        for (int jt = 0; jt < 2; jt++) {
            size_t off = (size_t)(base[jt] + doff) * 256 + k0 + q * 8;
            bh[jt] = *(const short8*)(gxhb + off);
            bl[jt] = *(const short8*)(gxlb + off);
        }
#pragma unroll
        for (int mt = 0; mt < 4; mt++)
#pragma unroll
            for (int jt = 0; jt < 2; jt++) {
                acc[mt][jt] = MFMA(ah[mt], bh[jt], acc[mt][jt]);
                acc[mt][jt] = MFMA(ah[mt], bl[jt], acc[mt][jt]);
                acc[mt][jt] = MFMA(al_[mt], bh[jt], acc[mt][jt]);
            }
    }

#pragma unroll
    for (int mt = 0; mt < 4; mt++)
#pragma unroll
        for (int jt = 0; jt < 2; jt++)
#pragma unroll
            for (int r = 0; r < 4; r++)
                Sp[w][(mt * 16 + q * 4 + r) * 32 + jt * 16 + lc] = acc[mt][jt][r];
    __syncthreads();

    float pa = prelu_a[0];
#pragma unroll
    for (int gi = 0; gi < 2; gi++) {
        int g = tid + gi * 256;
        int j = g & 31, mg = g >> 5;
        int m = mg * 4;
        int jj = j0 + j;
        if (jj >= 961) continue;
        float v[4];
#pragma unroll
        for (int i = 0; i < 4; i++) {
            int idx = (m + i) * 32 + j;
            v[i] = Sp[0][idx] + Sp[1][idx] + Sp[2][idx] + Sp[3][idx];
            v[i] = v[i] * sc[m + i] + sh[m + i];
            v[i] = v[i] >= 0.f ? v[i] : pa * v[i];
        }
        ushort_t a0, b0, a1, b1, a2, b2, a3, b3;
        split2(v[0], a0, b0); split2(v[1], a1, b1);
        split2(v[2], a2, b2); split2(v[3], a3, b3);
        *(ushort4*)(ebh + (size_t)jj * 64 + m) = make_ushort4(a0, a1, a2, a3);
        *(ushort4*)(ebl + (size_t)jj * 64 + m) = make_ushort4(b0, b1, b2, b3);
    }
}

// ---------------------------------------------------------------------
// HSPA: S = e^T e -> sparsemax (Michelot) -> P^T bf16. grid (B, 61).
// ---------------------------------------------------------------------
__global__ __launch_bounds__(512) void hspa_mfma_kernel(
    const ushort_t* __restrict__ eh, const ushort_t* __restrict__ el,
    ushort_t* __restrict__ PT)
{
    const int PITCH = 978;
    __shared__ float S[16 * 978];
    int b = blockIdx.x, nb = blockIdx.y;
    const ushort_t* ebh = eh + (size_t)b * 1024 * 64;
    const ushort_t* ebl = el + (size_t)b * 1024 * 64;
    ushort_t* Pb = PT + (size_t)b * 1024 * 992;
    int tid = threadIdx.x, w = tid >> 6, l = tid & 63, lc = l & 15, q = l >> 4;
    int n0 = nb * 16;

    short8 a0h = *(const short8*)(ebh + (size_t)(n0 + lc) * 64 + q * 8);
    short8 a0l = *(const short8*)(ebl + (size_t)(n0 + lc) * 64 + q * 8);
    short8 a1h = *(const short8*)(ebh + (size_t)(n0 + lc) * 64 + 32 + q * 8);
    short8 a1l = *(const short8*)(ebl + (size_t)(n0 + lc) * 64 + 32 + q * 8);

    for (int jt = w; jt < 61; jt += 8) {
        int j = jt * 16 + lc;
        short8 b0h = *(const short8*)(ebh + (size_t)j * 64 + q * 8);
        short8 b0l = *(const short8*)(ebl + (size_t)j * 64 + q * 8);
        short8 b1h = *(const short8*)(ebh + (size_t)j * 64 + 32 + q * 8);
        short8 b1l = *(const short8*)(ebl + (size_t)j * 64 + 32 + q * 8);
        floatx4 acc = (floatx4){0.f, 0.f, 0.f, 0.f};
        acc = MFMA(a0h, b0h, acc);
        acc = MFMA(a0h, b0l, acc);
        acc = MFMA(a0l, b0h, acc);
        acc = MFMA(a1h, b1h, acc);
        acc = MFMA(a1h, b1l, acc);
        acc = MFMA(a1l, b1h, acc);
#pragma unroll
        for (int r = 0; r < 4; r++) S[(q * 4 + r) * PITCH + j] = acc[r];
    }
    __syncthreads();

    int r0 = w * 2, r1 = w * 2 + 1;
    float sv0[16], sv1[16];
    float mx0 = -INFINITY, mx1 = -INFINITY;
#pragma unroll
    for (int t = 0; t < 16; t++) {
        int j = l + t * 64;
        float s0 = (j < 961) ? S[r0 * PITCH + j] : -INFINITY;
        float s1 = (j < 961) ? S[r1 * PITCH + j] : -INFINITY;
        sv0[t] = s0; sv1[t] = s1;
        mx0 = fmaxf(mx0, s0); mx1 = fmaxf(mx1, s1);
    }
    for (int off = 32; off; off >>= 1) {
        mx0 = fmaxf(mx0, __shfl_xor(mx0, off));
        mx1 = fmaxf(mx1, __shfl_xor(mx1, off));
    }
#pragma unroll
    for (int t = 0; t < 16; t++) { sv0[t] -= mx0; sv1[t] -= mx1; }

    float tau0 = -1.f, tau1 = -1.f;
    for (int it = 0; it < 16; it++) {
        float s0 = 0.f, c0 = 0.f, s1 = 0.f, c1 = 0.f;
#pragma unroll
        for (int t = 0; t < 16; t++) {
            if (sv0[t] > tau0) { s0 += sv0[t]; c0 += 1.f; }
            if (sv1[t] > tau1) { s1 += sv1[t]; c1 += 1.f; }
        }
        for (int off = 32; off; off >>= 1) {
            s0 += __shfl_xor(s0, off); c0 += __shfl_xor(c0, off);
            s1 += __shfl_xor(s1, off); c1 += __shfl_xor(c1, off);
        }
        float nt0 = (s0 - 1.f) / c0;
        float nt1 = (s1 - 1.f) / c1;
        bool conv = (nt0 == tau0) && (nt1 == tau1);
        tau0 = nt0; tau1 = nt1;
        if (conv) break;
    }
#pragma unroll
    for (int t = 0; t < 16; t++) {
        int j = l + t * 64;
        if (j < 976) {
            S[r0 * PITCH + j] = (j < 961) ? fmaxf(sv0[t] - tau0, 0.f) : 0.f;
            S[r1 * PITCH + j] = (j < 961) ? fmaxf(sv1[t] - tau1, 0.f) : 0.f;
        }
    }
    __syncthreads();

    for (int j = tid; j < 976; j += 512) {
        union { ushort_t u[8]; uint4 v; } p0, p1;
#pragma unroll
        for (int r = 0; r < 8; r++)  p0.u[r] = f2bf(S[r * PITCH + j]);
#pragma unroll
        for (int r = 0; r < 8; r++)  p1.u[r] = f2bf(S[(8 + r) * PITCH + j]);
        ushort_t* dst = Pb + (size_t)j * 992 + n0;
        *(uint4*)(dst) = p0.v;
        *(uint4*)(dst + 8) = p1.v;
    }
}

// ---------------------------------------------------------------------
// out = gat @ P + gat. grid (B, 16) batch-major.
// ---------------------------------------------------------------------
__global__ __launch_bounds__(256) void out_mfma_kernel(
    const ushort_t* __restrict__ gat_nf, const ushort_t* __restrict__ PT,
    float* __restrict__ out)
{
    int b = blockIdx.x, jb = blockIdx.y;
    const ushort_t* gb = gat_nf + (size_t)b * 256 * 992;
    const ushort_t* Pb = PT + (size_t)b * 1024 * 992;
    float* ob = out + (size_t)b * 256 * 961;
    int tid = threadIdx.x, w = tid >> 6, l = tid & 63, lc = l & 15, q = l >> 4;
    int m0 = w * 64, j0 = jb * 64;

    floatx4 acc[4][4];
#pragma unroll
    for (int i = 0; i < 4; i++)
#pragma unroll
        for (int j = 0; j < 4; j++) acc[i][j] = (floatx4){0.f, 0.f, 0.f, 0.f};

    for (int k0 = 0; k0 < 992; k0 += 32) {
        short8 a[4], bb[4];
#pragma unroll
        for (int mt = 0; mt < 4; mt++)
            a[mt] = *(const short8*)(gb + (size_t)(m0 + mt * 16 + lc) * 992 + k0 + q * 8);
#pragma unroll
        for (int jt = 0; jt < 4; jt++)
            bb[jt] = *(const short8*)(Pb + (size_t)(j0 + jt * 16 + lc) * 992 + k0 + q * 8);
#pragma unroll
        for (int mt = 0; mt < 4; mt++)
#pragma unroll
            for (int jt = 0; jt < 4; jt++)
                acc[mt][jt] = MFMA(a[mt], bb[jt], acc[mt][jt]);
    }
#pragma unroll
    for (int mt = 0; mt < 4; mt++) {
        int mb = m0 + mt * 16 + q * 4;
#pragma unroll
        for (int jt = 0; jt < 4; jt++) {
            int j = j0 + jt * 16 + lc;
            if (j >= 961) continue;
#pragma unroll
            for (int r = 0; r < 4; r++) {
                float g = bf2f(gb[(size_t)(mb + r) * 992 + j]);
                ob[(size_t)(mb + r) * 961 + j] = acc[mt][jt][r] + g;
            }
        }
    }
}

// =====================================================================
extern "C" void kernel_launch(void* const* d_in, const int* in_sizes, int n_in,
                              void* d_out, int out_size, void* d_ws, size_t ws_size,
                              hipStream_t stream)
{
    const float* zf      = (const float*)d_in[0];
    const float* xf      = (const float*)d_in[1];
    const float* Wq      = (const float*)d_in[2];
    const float* bq      = (const float*)d_in[3];
    const float* Ws      = (const float*)d_in[4];
    const float* bs      = (const float*)d_in[5];
    const float* Wg      = (const float*)d_in[6];
    const float* bg      = (const float*)d_in[7];
    const float* g_gamma = (const float*)d_in[8];
    const float* g_beta  = (const float*)d_in[9];
    const float* g_mean  = (const float*)d_in[10];
    const float* g_var   = (const float*)d_in[11];
    const float* Wfi     = (const float*)d_in[12];
    const float* bfi     = (const float*)d_in[13];
    const float* fi_gamma= (const float*)d_in[14];
    const float* fi_beta = (const float*)d_in[15];
    const float* fi_mean = (const float*)d_in[16];
    const float* fi_var  = (const float*)d_in[17];
    const float* Wm      = (const float*)d_in[18];
    const float* bm      = (const float*)d_in[19];
    const float* m_gamma = (const float*)d_in[20];
    const float* m_beta  = (const float*)d_in[21];
    const float* m_mean  = (const float*)d_in[22];
    const float* m_var   = (const float*)d_in[23];
    const float* prelu_a = (const float*)d_in[24];
    float* out = (float*)d_out;

    ushort_t* ws = (ushort_t*)d_ws;
    ushort_t* Wq_h  = ws + 0;         ushort_t* Wq_l  = ws + 65536;
    ushort_t* Ws_h  = ws + 131072;    ushort_t* Ws_l  = ws + 196608;
    ushort_t* Wg_h  = ws + 262144;    ushort_t* Wg_l  = ws + 327680;
    ushort_t* Wfi_h = ws + 393216;    ushort_t* Wfi_l = ws + 524288;
    ushort_t* wm_h  = ws + 655360;    ushort_t* wm_l  = ws + 802816;
    ushort_t* XT_h    = ws + 950272;      // 8,126,464 each
    ushort_t* XT_l    = ws + 9076736;
    ushort_t* xf_tT_h = ws + 17203200;
    ushort_t* xf_tT_l = ws + 25329664;
    ushort_t* zf_tT_h = ws + 33456128;    // 524,288 each
    ushort_t* zf_tT_l = ws + 33980416;
    ushort_t* zf_gT_h = ws + 34504704;
    ushort_t* zf_gT_l = ws + 35028992;
    ushort_t* gxT_h   = ws + 17203200;    // aliases xf_tT region (dead after attn)
    ushort_t* gxT_l   = ws + 26124288;
    ushort_t* xf_gT_h = ws + 35553280;
    ushort_t* xf_gT_l = ws + 43679744;
    ushort_t* gat_nf  = ws + 51806208;    // 8,126,464
    ushort_t* eT_h    = ws + 59932672;    // 2,097,152 each
    ushort_t* eT_l    = ws + 62029824;
    ushort_t* PT      = ws + 64126976;    // 32,505,856
    ushort_t* zfT_h   = ws + 96632832;    // 524,288 each
    ushort_t* zfT_l   = ws + 97157120;
    float* scsh       = (float*)(ws + 97681408);   // 2176 floats
    ushort_t* zgC_h   = ws + 97685760;    // 524,288 each
    ushort_t* zgC_l   = ws + 98210048;
    ushort_t* embT_h = XT_h;
    ushort_t* embT_l = XT_l;

    const float* sc_q  = scsh + 0,    *sh_q  = scsh + 256;
    const float* sc_s  = scsh + 512,  *sh_s  = scsh + 768;
    const float* sc_g  = scsh + 1024, *sh_g  = scsh + 1280;
    const float* sc_fi = scsh + 1536, *sh_fi = scsh + 1792;
    const float* sc_m  = scsh + 2048, *sh_m  = scsh + 2112;

    prep_all_kernel<<<1857, 256, 0, stream>>>(
        Wq, Ws, Wg, Wfi, Wm,
        bq, bs, bg, g_gamma, g_beta, g_mean, g_var,
        bfi, fi_gamma, fi_beta, fi_mean, fi_var,
        bm, m_gamma, m_beta, m_mean, m_var,
        Wq_h, Wq_l, Ws_h, Ws_l, Wg_h, Wg_l, Wfi_h, Wfi_l, wm_h, wm_l, scsh);

    transpose_in_kernel<<<dim3(31, 8, 32), 256, 0, stream>>>(xf, XT_h, XT_l, 961, 992);
    transpose_in_kernel<<<dim3(2, 8, 32), 256, 0, stream>>>(zf, zfT_h, zfT_l, 49, 64);

    // batch-major grids: all tiles of batch b land on XCD b%8 (L2 locality)
    // wide dualconv: blockIdx.y = (ntile<<1)|half; 16 n-tiles of 64 for xf
    dualconv_mfma_kernel<<<dim3(32, 32), 256, 0, stream>>>(
        XT_h, XT_l, Wq_h, Wq_l, Wg_h, Wg_l,
        sc_q, sh_q, sc_g, sh_g, 0, 1,
        xf_tT_h, xf_tT_l, xf_gT_h, xf_gT_l,
        nullptr, nullptr, 0, 256, 961, 992, 992);
    dualconv_mfma_kernel<<<dim3(32, 2), 256, 0, stream>>>(
        zfT_h, zfT_l, Ws_h, Ws_l, Wg_h, Wg_l,
        sc_s, sh_s, sc_g, sh_g, 0, 1,
        zf_tT_h, zf_tT_l, zf_gT_h, zf_gT_l,
        zgC_h, zgC_l, 64, 256, 49, 64, 64);

    attn_mfma_kernel<<<dim3(32, 16), 256, 0, stream>>>(
        xf_tT_h, xf_tT_l, zf_tT_h, zf_tT_l, zgC_h, zgC_l, embT_h, embT_l);

    halo_zero_kernel<<<16, 256, 0, stream>>>(gxT_h, gxT_l);

    fi_mfma_kernel<<<dim3(32, 31), 256, 0, stream>>>(
        embT_h, embT_l, xf_gT_h, xf_gT_l, Wfi_h, Wfi_l, sc_fi, sh_fi,
        gxT_h, gxT_l, gat_nf);

    conv3x3_mfma_kernel<<<dim3(32, 31), 256, 0, stream>>>(
        gxT_h, gxT_l, wm_h, wm_l, sc_m, sh_m, prelu_a, eT_h, eT_l);

    hspa_mfma_kernel<<<dim3(32, 61), 512, 0, stream>>>(eT_h, eT_l, PT);

    out_mfma_kernel<<<dim3(32, 16), 256, 0, stream>>>(gat_nf, PT, out);
}